// Round 8
// baseline (157.194 us; speedup 1.0000x reference)
//
#include <hip/hip_runtime.h>
#include <math.h>

#define B_DIM 128
#define C_DIM 2048
#define HW2   196

typedef __attribute__((ext_vector_type(8))) short bf16x8;
typedef __attribute__((ext_vector_type(4))) float f32x4;

__device__ __forceinline__ unsigned short f2bf(float f) {
  unsigned u = __float_as_uint(f);
  u += 0x7FFFu + ((u >> 16) & 1u);     // RNE
  return (unsigned short)(u >> 16);
}

// ---------------------------------------------------------------------------
// K1: per-(b,c) 14x14 tile -> global max (mp) + 4-scale adaptive avg-pool max.
// Register-resident separable pooling. Non-temporal x loads (read-once stream).
// ---------------------------------------------------------------------------
__global__ __launch_bounds__(256) void pool_max_kernel(
    const float* __restrict__ x, float* __restrict__ mp, float* __restrict__ ms) {
  __shared__ float lds[4][4][208];
  const int tid  = threadIdx.x;
  const int w    = tid >> 6;
  const int lane = tid & 63;
  const int g    = lane >> 4;
  const int c    = lane & 15;
  const size_t waveBase = (size_t)blockIdx.x * 16 + w * 4;

  const float* src = x + waveBase * HW2;
  #pragma unroll
  for (int j = 0; j < 4; ++j) {
    int f = lane + 64 * j;
    if (f < 196) {
      int t = (f * 669) >> 15;       // f / 49
      f32x4 v = __builtin_nontemporal_load((const f32x4*)(src + f * 4));
      *(f32x4*)&lds[w][t][(f - 49 * t) * 4] = v;
    }
  }

  float xv[14];
  const float* col = &lds[w][g][c];
  #pragma unroll
  for (int r = 0; r < 14; ++r) xv[r] = col[r * 14];

  float cmax = (c < 14) ? xv[0] : -INFINITY;
  #pragma unroll
  for (int r = 1; r < 14; ++r) if (c < 14) cmax = fmaxf(cmax, xv[r]);
  #pragma unroll
  for (int off = 8; off > 0; off >>= 1) cmax = fmaxf(cmax, __shfl_xor(cmax, off));

  float P[15];
  P[0] = 0.f;
  #pragma unroll
  for (int r = 0; r < 14; ++r) P[r + 1] = P[r] + xv[r];

  float sm0, sm1, sm2, sm3;

  { // k=4
    constexpr int rs[4] = {0, 3, 7, 10}, re[4] = {4, 7, 11, 14};
    const bool valid = (0x489u >> c) & 1;
    float vmax = -INFINITY;
    #pragma unroll
    for (int i = 0; i < 4; ++i) {
      float v  = P[re[i]] - P[rs[i]];
      float w2 = v + __shfl_down(v, 1);
      float w4 = w2 + __shfl_down(w2, 2);
      vmax = fmaxf(vmax, valid ? w4 : -INFINITY);
    }
    #pragma unroll
    for (int off = 8; off > 0; off >>= 1) vmax = fmaxf(vmax, __shfl_xor(vmax, off));
    sm0 = vmax * 0.0625f;
  }
  { // k=5
    constexpr int rs[5] = {0, 2, 5, 8, 11}, re[5] = {3, 6, 9, 12, 14};
    constexpr float srl[5] = {1.f/3.f, 0.25f, 0.25f, 0.25f, 1.f/3.f};
    const bool valid = (0x925u >> c) & 1;
    const bool is3   = (0x801u >> c) & 1;
    const float invc = is3 ? (1.f/3.f) : 0.25f;
    float vmax = -INFINITY;
    #pragma unroll
    for (int i = 0; i < 5; ++i) {
      float v  = P[re[i]] - P[rs[i]];
      float d1 = __shfl_down(v, 1);
      float d2 = __shfl_down(v, 2);
      float w2 = v + d1;
      float w3 = w2 + d2;
      float w4 = w2 + __shfl_down(w2, 2);
      float wv = (is3 ? w3 : w4) * invc * srl[i];
      vmax = fmaxf(vmax, valid ? wv : -INFINITY);
    }
    #pragma unroll
    for (int off = 8; off > 0; off >>= 1) vmax = fmaxf(vmax, __shfl_xor(vmax, off));
    sm1 = vmax;
  }
  { // k=7
    constexpr int rs[7] = {0, 2, 4, 6, 8, 10, 12};
    const bool valid = (0x1555u >> c) & 1;
    float vmax = -INFINITY;
    #pragma unroll
    for (int i = 0; i < 7; ++i) {
      float v  = P[rs[i] + 2] - P[rs[i]];
      float w2 = v + __shfl_down(v, 1);
      vmax = fmaxf(vmax, valid ? w2 : -INFINITY);
    }
    #pragma unroll
    for (int off = 8; off > 0; off >>= 1) vmax = fmaxf(vmax, __shfl_xor(vmax, off));
    sm2 = vmax * 0.25f;
  }
  { // k=11
    constexpr int rs[11] = {0, 1, 2, 3, 5, 6, 7, 8, 10, 11, 12};
    constexpr int re[11] = {2, 3, 4, 6, 7, 8, 9, 11, 12, 13, 14};
    constexpr float srl[11] = {0.5f, 0.5f, 0.5f, 1.f/3.f, 0.5f, 0.5f, 0.5f,
                               1.f/3.f, 0.5f, 0.5f, 0.5f};
    const bool valid = (0x1DEFu >> c) & 1;
    const bool is3   = (0x108u >> c) & 1;
    const float invc = is3 ? (1.f/3.f) : 0.5f;
    float vmax = -INFINITY;
    #pragma unroll
    for (int i = 0; i < 11; ++i) {
      float v  = P[re[i]] - P[rs[i]];
      float d1 = __shfl_down(v, 1);
      float d2 = __shfl_down(v, 2);
      float w2 = v + d1;
      float w3 = w2 + d2;
      float wv = (is3 ? w3 : w2) * invc * srl[i];
      vmax = fmaxf(vmax, valid ? wv : -INFINITY);
    }
    #pragma unroll
    for (int off = 8; off > 0; off >>= 1) vmax = fmaxf(vmax, __shfl_xor(vmax, off));
    sm3 = vmax;
  }

  if (c == 0) {
    size_t T = waveBase + g;
    mp[T] = cmax;
    *(float4*)&ms[T * 4] = make_float4(sm0, sm1, sm2, sm3);
  }
}

// ---------------------------------------------------------------------------
// K2: mp column stats + affine params (hh head, hf second half)
// ---------------------------------------------------------------------------
__global__ __launch_bounds__(256) void statsmp_kernel(
    const float* __restrict__ mp,
    const float* __restrict__ hh_g1, const float* __restrict__ hh_b1,
    const float* __restrict__ hf_g1, const float* __restrict__ hf_b1,
    float* __restrict__ mean_mp, float* __restrict__ rstd_mp,
    float* __restrict__ s_h, float* __restrict__ t_h,
    float* __restrict__ sf2, float* __restrict__ tf2) {
  const int ci = threadIdx.x & 15;
  const int g  = threadIdx.x >> 4;
  const int c  = blockIdx.x * 16 + ci;
  float s = 0.f, q = 0.f;
  #pragma unroll
  for (int r = 0; r < 8; ++r) {
    float v = mp[(size_t)(g * 8 + r) * C_DIM + c];
    s += v; q += v * v;
  }
  __shared__ float ss[16][16], qq[16][16];
  ss[g][ci] = s; qq[g][ci] = q;
  __syncthreads();
  if (g == 0) {
    float S = 0.f, Q = 0.f;
    #pragma unroll
    for (int j = 0; j < 16; ++j) { S += ss[j][ci]; Q += qq[j][ci]; }
    float m = S * (1.f / B_DIM);
    float var = Q * (1.f / B_DIM) - m * m;
    if (var < 0.f) var = 0.f;
    float r = rsqrtf(var + 1e-5f);
    mean_mp[c] = m; rstd_mp[c] = r;
    float a = r * hh_g1[c];        s_h[c] = a; t_h[c] = hh_b1[c] - m * a;
    float b = r * hf_g1[2048 + c]; sf2[c] = b; tf2[c] = hf_b1[2048 + c] - m * b;
  }
}

// ---------------------------------------------------------------------------
// K3: gate (BN+ELU+linear+argmax) fused with gated scale select -> pool
// ---------------------------------------------------------------------------
__global__ void gate_select_kernel(
    const float* __restrict__ mp,
    const float* __restrict__ mean, const float* __restrict__ rstd,
    const float* __restrict__ gg, const float* __restrict__ gb,
    const float* __restrict__ gw, const float* __restrict__ gbias,
    const float* __restrict__ ms, float* __restrict__ pool) {
  const int b = blockIdx.x;
  const int t = threadIdx.x;
  float s0 = 0.f, s1 = 0.f, s2 = 0.f, s3 = 0.f;
  for (int c = t; c < C_DIM; c += 256) {
    float v = mp[(size_t)b * C_DIM + c];
    float xn = (v - mean[c]) * rstd[c] * gg[c] + gb[c];
    float e = xn > 0.f ? xn : expm1f(xn);
    s0 += e * gw[c];
    s1 += e * gw[C_DIM + c];
    s2 += e * gw[2 * C_DIM + c];
    s3 += e * gw[3 * C_DIM + c];
  }
  __shared__ float red[4][256];
  __shared__ int ssel;
  red[0][t] = s0; red[1][t] = s1; red[2][t] = s2; red[3][t] = s3;
  __syncthreads();
  for (int st = 128; st > 0; st >>= 1) {
    if (t < st) {
      red[0][t] += red[0][t + st];
      red[1][t] += red[1][t + st];
      red[2][t] += red[2][t + st];
      red[3][t] += red[3][t + st];
    }
    __syncthreads();
  }
  if (t == 0) {
    float best = red[0][0] + gbias[0];
    int bi = 0;
    for (int j = 1; j < 4; ++j) {
      float l = red[j][0] + gbias[j];
      if (l > best) { best = l; bi = j; }
    }
    ssel = bi;
  }
  __syncthreads();
  const int sel = ssel;
  for (int c = t; c < C_DIM; c += 256)
    pool[(size_t)b * C_DIM + c] = ms[((size_t)b * C_DIM + c) * 4 + sel];
}

// ---------------------------------------------------------------------------
// K4: expert GEMM, bf16 MFMA. BM=128 BN=64 BK=64, grid (32, z=8), Kc=256.
// ---------------------------------------------------------------------------
__global__ __launch_bounds__(256) void gemm_e_mfma_kernel(
    const float* __restrict__ A, const float* __restrict__ W,
    float* __restrict__ P) {
  __shared__ __align__(16) short As[128 * 64];
  __shared__ __align__(16) short Bs[64 * 64];
  const int t = threadIdx.x;
  const int n0 = blockIdx.x << 6;
  const int kbeg = blockIdx.y << 8;          // Kc = 256

  const int rowA = t >> 1, koffA = (t & 1) << 5;
  const int rowB = t >> 2, koffB = (t & 3) << 4;

  const int lane = t & 63, wav = t >> 6;
  const int r = lane & 15, kb = lane >> 4;
  int aoff[2][2], boff[2][4];
  #pragma unroll
  for (int kk = 0; kk < 2; ++kk) {
    #pragma unroll
    for (int mi = 0; mi < 2; ++mi) {
      int row = wav * 32 + mi * 16 + r;
      aoff[kk][mi] = row * 128 + ((((kk << 2) + kb) ^ (row & 7)) << 4);
    }
    #pragma unroll
    for (int ni = 0; ni < 4; ++ni) {
      int cl = ni * 16 + r;
      boff[kk][ni] = cl * 128 + ((((kk << 2) + kb) ^ (cl & 7)) << 4);
    }
  }

  f32x4 acc[2][4];
  #pragma unroll
  for (int mi = 0; mi < 2; ++mi)
    #pragma unroll
    for (int ni = 0; ni < 4; ++ni)
      acc[mi][ni] = (f32x4){0.f, 0.f, 0.f, 0.f};

  for (int kt = 0; kt < 256; kt += 64) {
    const int kg = kbeg + kt;
    const float4* ap = (const float4*)&A[(size_t)rowA * 2048 + kg + koffA];
    const float4* bp = (const float4*)&W[(size_t)(n0 + rowB) * 2048 + kg + koffB];
    float4 fa[8], fb[4];
    #pragma unroll
    for (int j = 0; j < 8; ++j) fa[j] = ap[j];
    #pragma unroll
    for (int j = 0; j < 4; ++j) fb[j] = bp[j];
    __syncthreads();
    #pragma unroll
    for (int j = 0; j < 4; ++j) {
      bf16x8 v;
      v[0] = (short)f2bf(fa[2*j].x);   v[1] = (short)f2bf(fa[2*j].y);
      v[2] = (short)f2bf(fa[2*j].z);   v[3] = (short)f2bf(fa[2*j].w);
      v[4] = (short)f2bf(fa[2*j+1].x); v[5] = (short)f2bf(fa[2*j+1].y);
      v[6] = (short)f2bf(fa[2*j+1].z); v[7] = (short)f2bf(fa[2*j+1].w);
      int slot = (koffA >> 3) + j;
      *(bf16x8*)((char*)As + rowA * 128 + ((slot ^ (rowA & 7)) << 4)) = v;
    }
    #pragma unroll
    for (int j = 0; j < 2; ++j) {
      bf16x8 v;
      v[0] = (short)f2bf(fb[2*j].x);   v[1] = (short)f2bf(fb[2*j].y);
      v[2] = (short)f2bf(fb[2*j].z);   v[3] = (short)f2bf(fb[2*j].w);
      v[4] = (short)f2bf(fb[2*j+1].x); v[5] = (short)f2bf(fb[2*j+1].y);
      v[6] = (short)f2bf(fb[2*j+1].z); v[7] = (short)f2bf(fb[2*j+1].w);
      int slot = (koffB >> 3) + j;
      *(bf16x8*)((char*)Bs + rowB * 128 + ((slot ^ (rowB & 7)) << 4)) = v;
    }
    __syncthreads();
    #pragma unroll
    for (int kk = 0; kk < 2; ++kk) {
      bf16x8 a0 = *(bf16x8*)((char*)As + aoff[kk][0]);
      bf16x8 a1 = *(bf16x8*)((char*)As + aoff[kk][1]);
      bf16x8 b0 = *(bf16x8*)((char*)Bs + boff[kk][0]);
      bf16x8 b1 = *(bf16x8*)((char*)Bs + boff[kk][1]);
      bf16x8 b2 = *(bf16x8*)((char*)Bs + boff[kk][2]);
      bf16x8 b3 = *(bf16x8*)((char*)Bs + boff[kk][3]);
      acc[0][0] = __builtin_amdgcn_mfma_f32_16x16x32_bf16(a0, b0, acc[0][0], 0, 0, 0);
      acc[0][1] = __builtin_amdgcn_mfma_f32_16x16x32_bf16(a0, b1, acc[0][1], 0, 0, 0);
      acc[0][2] = __builtin_amdgcn_mfma_f32_16x16x32_bf16(a0, b2, acc[0][2], 0, 0, 0);
      acc[0][3] = __builtin_amdgcn_mfma_f32_16x16x32_bf16(a0, b3, acc[0][3], 0, 0, 0);
      acc[1][0] = __builtin_amdgcn_mfma_f32_16x16x32_bf16(a1, b0, acc[1][0], 0, 0, 0);
      acc[1][1] = __builtin_amdgcn_mfma_f32_16x16x32_bf16(a1, b1, acc[1][1], 0, 0, 0);
      acc[1][2] = __builtin_amdgcn_mfma_f32_16x16x32_bf16(a1, b2, acc[1][2], 0, 0, 0);
      acc[1][3] = __builtin_amdgcn_mfma_f32_16x16x32_bf16(a1, b3, acc[1][3], 0, 0, 0);
    }
  }

  float* Pz = P + ((size_t)blockIdx.y << 18);
  #pragma unroll
  for (int mi = 0; mi < 2; ++mi) {
    int row = wav * 32 + mi * 16 + kb * 4;
    #pragma unroll
    for (int ni = 0; ni < 4; ++ni) {
      int cl = n0 + ni * 16 + r;
      #pragma unroll
      for (int g2 = 0; g2 < 4; ++g2)
        Pz[(size_t)(row + g2) * 2048 + cl] = acc[mi][ni][g2];
    }
  }
}

// ---------------------------------------------------------------------------
// K5: expert fused epilogue (reduce 8 partials + bias -> BN -> relu -> stats)
// ---------------------------------------------------------------------------
__global__ __launch_bounds__(256) void expert_fused_kernel(
    const float* __restrict__ Pe, const float* __restrict__ e_b,
    const float* __restrict__ e_g, const float* __restrict__ e_bb,
    const float* __restrict__ hl_g1, const float* __restrict__ hl_b1,
    const float* __restrict__ hf_g1, const float* __restrict__ hf_b1,
    float* __restrict__ xl,
    float* __restrict__ s_l, float* __restrict__ t_l,
    float* __restrict__ sf1, float* __restrict__ tf1) {
  const int ci = threadIdx.x & 15;
  const int g  = threadIdx.x >> 4;
  const int c  = blockIdx.x * 16 + ci;
  float v[8];
  float s = 0.f, q = 0.f;
  const float bias = e_b[c];
  #pragma unroll
  for (int r = 0; r < 8; ++r) {
    const size_t row = g * 8 + r;
    float acc = bias;
    #pragma unroll
    for (int z = 0; z < 8; ++z)
      acc += Pe[((size_t)z << 18) + row * 2048 + c];
    v[r] = acc; s += acc; q += acc * acc;
  }
  __shared__ float ss[16][16], qq[16][16];
  __shared__ float sm[16], sr[16];
  ss[g][ci] = s; qq[g][ci] = q;
  __syncthreads();
  if (g == 0) {
    float S = 0.f, Q = 0.f;
    #pragma unroll
    for (int j = 0; j < 16; ++j) { S += ss[j][ci]; Q += qq[j][ci]; }
    float m = S * (1.f / B_DIM);
    float var = Q * (1.f / B_DIM) - m * m;
    if (var < 0.f) var = 0.f;
    sm[ci] = m; sr[ci] = rsqrtf(var + 1e-5f);
  }
  __syncthreads();
  const float m = sm[ci], rst = sr[ci];
  const float eg = e_g[c], eb2 = e_bb[c];
  float s2 = 0.f, q2 = 0.f;
  #pragma unroll
  for (int r = 0; r < 8; ++r) {
    float xv = fmaxf((v[r] - m) * rst * eg + eb2, 0.f);
    xl[(size_t)(g * 8 + r) * 2048 + c] = xv;
    s2 += xv; q2 += xv * xv;
  }
  __syncthreads();
  ss[g][ci] = s2; qq[g][ci] = q2;
  __syncthreads();
  if (g == 0) {
    float S = 0.f, Q = 0.f;
    #pragma unroll
    for (int j = 0; j < 16; ++j) { S += ss[j][ci]; Q += qq[j][ci]; }
    float mm = S * (1.f / B_DIM);
    float var = Q * (1.f / B_DIM) - mm * mm;
    if (var < 0.f) var = 0.f;
    float rr = rsqrtf(var + 1e-5f);
    float a = rr * hl_g1[c]; s_l[c] = a; t_l[c] = hl_b1[c] - mm * a;
    float b = rr * hf_g1[c]; sf1[c] = b; tf1[c] = hf_b1[c] - mm * b;
  }
}

// ---------------------------------------------------------------------------
// K6: combined head-linear1 GEMM, bf16 MFMA, BN1 affine folded into A staging.
// grid (32, 8): jobs [0,8)=hl, [8,16)=hh, [16,32)=hf. Kc: l/h=256, f=512.
// ---------------------------------------------------------------------------
__global__ __launch_bounds__(256) void gemm_w1_mfma_kernel(
    const float* __restrict__ xl, const float* __restrict__ mp,
    const float* __restrict__ s_l, const float* __restrict__ t_l,
    const float* __restrict__ s_h, const float* __restrict__ t_h,
    const float* __restrict__ sf1, const float* __restrict__ tf1,
    const float* __restrict__ sf2, const float* __restrict__ tf2,
    const float* __restrict__ hl_w1, const float* __restrict__ hh_w1,
    const float* __restrict__ hf_w1,
    float* __restrict__ P_l, float* __restrict__ P_h, float* __restrict__ P_f) {
  __shared__ __align__(16) short As[128 * 64];
  __shared__ __align__(16) short Bs[64 * 64];
  const int jx = blockIdx.x;
  const int z  = blockIdx.y;
  const float *A, *S, *T, *Wt;
  float* P;
  int N, Kdim, n0, kA0, kW0, Kc;
  if (jx < 8) {
    N = 512; Kdim = 2048; Kc = 256; Wt = hl_w1; n0 = jx << 6;
    kW0 = z * 256; kA0 = kW0; A = xl; S = s_l; T = t_l;
    P = P_l + ((size_t)z << 16);
  } else if (jx < 16) {
    N = 512; Kdim = 2048; Kc = 256; Wt = hh_w1; n0 = (jx - 8) << 6;
    kW0 = z * 256; kA0 = kW0; A = mp; S = s_h; T = t_h;
    P = P_h + ((size_t)z << 16);
  } else {
    N = 1024; Kdim = 4096; Kc = 512; Wt = hf_w1; n0 = (jx - 16) << 6;
    kW0 = z * 512;
    if (kW0 >= 2048) { A = mp; S = sf2; T = tf2; kA0 = kW0 - 2048; }
    else             { A = xl; S = sf1; T = tf1; kA0 = kW0; }
    P = P_f + ((size_t)z << 17);
  }
  const int t = threadIdx.x;
  const int rowA = t >> 1, koffA = (t & 1) << 5;
  const int rowB = t >> 2, koffB = (t & 3) << 4;

  const int lane = t & 63, wav = t >> 6;
  const int r = lane & 15, kb = lane >> 4;
  int aoff[2][2], boff[2][4];
  #pragma unroll
  for (int kk = 0; kk < 2; ++kk) {
    #pragma unroll
    for (int mi = 0; mi < 2; ++mi) {
      int row = wav * 32 + mi * 16 + r;
      aoff[kk][mi] = row * 128 + ((((kk << 2) + kb) ^ (row & 7)) << 4);
    }
    #pragma unroll
    for (int ni = 0; ni < 4; ++ni) {
      int cl = ni * 16 + r;
      boff[kk][ni] = cl * 128 + ((((kk << 2) + kb) ^ (cl & 7)) << 4);
    }
  }

  f32x4 acc[2][4];
  #pragma unroll
  for (int mi = 0; mi < 2; ++mi)
    #pragma unroll
    for (int ni = 0; ni < 4; ++ni)
      acc[mi][ni] = (f32x4){0.f, 0.f, 0.f, 0.f};

  for (int kt = 0; kt < Kc; kt += 64) {
    const int ka = kA0 + kt + koffA;
    const float4* ap = (const float4*)&A[(size_t)rowA * 2048 + ka];
    const float4* sp = (const float4*)&S[ka];
    const float4* tp = (const float4*)&T[ka];
    const float4* bp = (const float4*)&Wt[(size_t)(n0 + rowB) * Kdim + kW0 + kt + koffB];
    float4 fa[8], fb[4];
    #pragma unroll
    for (int j = 0; j < 8; ++j) fa[j] = ap[j];
    #pragma unroll
    for (int j = 0; j < 8; ++j) {
      float4 s4 = sp[j], t4 = tp[j];
      fa[j].x = fmaf(fa[j].x, s4.x, t4.x);
      fa[j].y = fmaf(fa[j].y, s4.y, t4.y);
      fa[j].z = fmaf(fa[j].z, s4.z, t4.z);
      fa[j].w = fmaf(fa[j].w, s4.w, t4.w);
    }
    #pragma unroll
    for (int j = 0; j < 4; ++j) fb[j] = bp[j];
    __syncthreads();
    #pragma unroll
    for (int j = 0; j < 4; ++j) {
      bf16x8 v;
      v[0] = (short)f2bf(fa[2*j].x);   v[1] = (short)f2bf(fa[2*j].y);
      v[2] = (short)f2bf(fa[2*j].z);   v[3] = (short)f2bf(fa[2*j].w);
      v[4] = (short)f2bf(fa[2*j+1].x); v[5] = (short)f2bf(fa[2*j+1].y);
      v[6] = (short)f2bf(fa[2*j+1].z); v[7] = (short)f2bf(fa[2*j+1].w);
      int slot = (koffA >> 3) + j;
      *(bf16x8*)((char*)As + rowA * 128 + ((slot ^ (rowA & 7)) << 4)) = v;
    }
    #pragma unroll
    for (int j = 0; j < 2; ++j) {
      bf16x8 v;
      v[0] = (short)f2bf(fb[2*j].x);   v[1] = (short)f2bf(fb[2*j].y);
      v[2] = (short)f2bf(fb[2*j].z);   v[3] = (short)f2bf(fb[2*j].w);
      v[4] = (short)f2bf(fb[2*j+1].x); v[5] = (short)f2bf(fb[2*j+1].y);
      v[6] = (short)f2bf(fb[2*j+1].z); v[7] = (short)f2bf(fb[2*j+1].w);
      int slot = (koffB >> 3) + j;
      *(bf16x8*)((char*)Bs + rowB * 128 + ((slot ^ (rowB & 7)) << 4)) = v;
    }
    __syncthreads();
    #pragma unroll
    for (int kk = 0; kk < 2; ++kk) {
      bf16x8 a0 = *(bf16x8*)((char*)As + aoff[kk][0]);
      bf16x8 a1 = *(bf16x8*)((char*)As + aoff[kk][1]);
      bf16x8 b0 = *(bf16x8*)((char*)Bs + boff[kk][0]);
      bf16x8 b1 = *(bf16x8*)((char*)Bs + boff[kk][1]);
      bf16x8 b2 = *(bf16x8*)((char*)Bs + boff[kk][2]);
      bf16x8 b3 = *(bf16x8*)((char*)Bs + boff[kk][3]);
      acc[0][0] = __builtin_amdgcn_mfma_f32_16x16x32_bf16(a0, b0, acc[0][0], 0, 0, 0);
      acc[0][1] = __builtin_amdgcn_mfma_f32_16x16x32_bf16(a0, b1, acc[0][1], 0, 0, 0);
      acc[0][2] = __builtin_amdgcn_mfma_f32_16x16x32_bf16(a0, b2, acc[0][2], 0, 0, 0);
      acc[0][3] = __builtin_amdgcn_mfma_f32_16x16x32_bf16(a0, b3, acc[0][3], 0, 0, 0);
      acc[1][0] = __builtin_amdgcn_mfma_f32_16x16x32_bf16(a1, b0, acc[1][0], 0, 0, 0);
      acc[1][1] = __builtin_amdgcn_mfma_f32_16x16x32_bf16(a1, b1, acc[1][1], 0, 0, 0);
      acc[1][2] = __builtin_amdgcn_mfma_f32_16x16x32_bf16(a1, b2, acc[1][2], 0, 0, 0);
      acc[1][3] = __builtin_amdgcn_mfma_f32_16x16x32_bf16(a1, b3, acc[1][3], 0, 0, 0);
    }
  }

  #pragma unroll
  for (int mi = 0; mi < 2; ++mi) {
    int row = wav * 32 + mi * 16 + kb * 4;
    #pragma unroll
    for (int ni = 0; ni < 4; ++ni) {
      int cl = n0 + ni * 16 + r;
      #pragma unroll
      for (int g2 = 0; g2 < 4; ++g2)
        P[(size_t)(row + g2) * N + cl] = acc[mi][ni][g2];
    }
  }
}

// ---------------------------------------------------------------------------
// K7: heads fused epilogue (reduce 8 partial slices + bias -> BN -> ELU)
// ---------------------------------------------------------------------------
__global__ __launch_bounds__(256) void heads_fused_kernel(
    const float* __restrict__ P_l, const float* __restrict__ P_h,
    const float* __restrict__ P_f,
    const float* __restrict__ bl1, const float* __restrict__ bh1,
    const float* __restrict__ bf1,
    const float* __restrict__ g2l, const float* __restrict__ b2l,
    const float* __restrict__ g2h, const float* __restrict__ b2h,
    const float* __restrict__ g2f, const float* __restrict__ b2f,
    float* __restrict__ a2_l, float* __restrict__ a2_h, float* __restrict__ a2_f) {
  const int ci = threadIdx.x & 15;
  const int g  = threadIdx.x >> 4;
  const int cj = blockIdx.x * 16 + ci;
  const float *P, *bi, *g2, *b2;
  float* out;
  int N, cc;
  if (cj < 512)       { P = P_l; bi = bl1; g2 = g2l; b2 = b2l; out = a2_l; N = 512;  cc = cj; }
  else if (cj < 1024) { P = P_h; bi = bh1; g2 = g2h; b2 = b2h; out = a2_h; N = 512;  cc = cj - 512; }
  else                { P = P_f; bi = bf1; g2 = g2f; b2 = b2f; out = a2_f; N = 1024; cc = cj - 1024; }
  const size_t sstride = (size_t)N * 128;
  float v[8];
  float s = 0.f, q = 0.f;
  const float bias = bi[cc];
  #pragma unroll
  for (int r = 0; r < 8; ++r) {
    const size_t row = g * 8 + r;
    float acc = bias;
    #pragma unroll
    for (int z = 0; z < 8; ++z)
      acc += P[(size_t)z * sstride + row * N + cc];
    v[r] = acc; s += acc; q += acc * acc;
  }
  __shared__ float ss[16][16], qq[16][16];
  __shared__ float sm[16], sr[16];
  ss[g][ci] = s; qq[g][ci] = q;
  __syncthreads();
  if (g == 0) {
    float S = 0.f, Q = 0.f;
    #pragma unroll
    for (int j = 0; j < 16; ++j) { S += ss[j][ci]; Q += qq[j][ci]; }
    float m = S * (1.f / B_DIM);
    float var = Q * (1.f / B_DIM) - m * m;
    if (var < 0.f) var = 0.f;
    sm[ci] = m; sr[ci] = rsqrtf(var + 1e-5f);
  }
  __syncthreads();
  const float m = sm[ci], rr = sr[ci];
  const float gg = g2[cc], bb = b2[cc];
  #pragma unroll
  for (int r = 0; r < 8; ++r) {
    float xn = (v[r] - m) * rr * gg + bb;
    out[(size_t)(g * 8 + r) * N + cc] = xn > 0.f ? xn : expm1f(xn);
  }
}

// ---------------------------------------------------------------------------
// K8: head-linear2 as bf16 MFMA, full K per block, writes out directly + bias.
// grid: 12 blocks. jx<4: low (K=512), jx<8: high (K=512), else: full (K=1024).
// n0 = (jx&3)*64; cols >= 200 guarded. BM=128 covers all rows.
// ---------------------------------------------------------------------------
__global__ __launch_bounds__(256) void gemm_w2_mfma_kernel(
    const float* __restrict__ a2_l, const float* __restrict__ a2_h,
    const float* __restrict__ a2_f,
    const float* __restrict__ hl_w2, const float* __restrict__ hh_w2,
    const float* __restrict__ hf_w2,
    const float* __restrict__ bl2, const float* __restrict__ bh2,
    const float* __restrict__ bf2,
    float* __restrict__ out) {
  __shared__ __align__(16) short As[128 * 64];
  __shared__ __align__(16) short Bs[64 * 64];
  const int jx = blockIdx.x;
  const float *A, *Wt, *bi;
  int K, outOff;
  if (jx < 4)      { A = a2_l; Wt = hl_w2; bi = bl2; K = 512;  outOff = 0; }
  else if (jx < 8) { A = a2_h; Wt = hh_w2; bi = bh2; K = 512;  outOff = 25600; }
  else             { A = a2_f; Wt = hf_w2; bi = bf2; K = 1024; outOff = 51200; }
  const int n0 = (jx & 3) << 6;

  const int t = threadIdx.x;
  const int rowA = t >> 1, koffA = (t & 1) << 5;
  const int rowB = t >> 2, koffB = (t & 3) << 4;

  const int lane = t & 63, wav = t >> 6;
  const int r = lane & 15, kb = lane >> 4;
  int aoff[2][2], boff[2][4];
  #pragma unroll
  for (int kk = 0; kk < 2; ++kk) {
    #pragma unroll
    for (int mi = 0; mi < 2; ++mi) {
      int row = wav * 32 + mi * 16 + r;
      aoff[kk][mi] = row * 128 + ((((kk << 2) + kb) ^ (row & 7)) << 4);
    }
    #pragma unroll
    for (int ni = 0; ni < 4; ++ni) {
      int cl = ni * 16 + r;
      boff[kk][ni] = cl * 128 + ((((kk << 2) + kb) ^ (cl & 7)) << 4);
    }
  }

  f32x4 acc[2][4];
  #pragma unroll
  for (int mi = 0; mi < 2; ++mi)
    #pragma unroll
    for (int ni = 0; ni < 4; ++ni)
      acc[mi][ni] = (f32x4){0.f, 0.f, 0.f, 0.f};

  const int wrow = n0 + rowB;
  const float4 z4 = make_float4(0.f, 0.f, 0.f, 0.f);
  for (int kt = 0; kt < K; kt += 64) {
    const float4* ap = (const float4*)&A[(size_t)rowA * K + kt + koffA];
    float4 fa[8], fb[4];
    #pragma unroll
    for (int j = 0; j < 8; ++j) fa[j] = ap[j];
    if (wrow < 200) {
      const float4* bp = (const float4*)&Wt[(size_t)wrow * K + kt + koffB];
      #pragma unroll
      for (int j = 0; j < 4; ++j) fb[j] = bp[j];
    } else {
      #pragma unroll
      for (int j = 0; j < 4; ++j) fb[j] = z4;
    }
    __syncthreads();
    #pragma unroll
    for (int j = 0; j < 4; ++j) {
      bf16x8 v;
      v[0] = (short)f2bf(fa[2*j].x);   v[1] = (short)f2bf(fa[2*j].y);
      v[2] = (short)f2bf(fa[2*j].z);   v[3] = (short)f2bf(fa[2*j].w);
      v[4] = (short)f2bf(fa[2*j+1].x); v[5] = (short)f2bf(fa[2*j+1].y);
      v[6] = (short)f2bf(fa[2*j+1].z); v[7] = (short)f2bf(fa[2*j+1].w);
      int slot = (koffA >> 3) + j;
      *(bf16x8*)((char*)As + rowA * 128 + ((slot ^ (rowA & 7)) << 4)) = v;
    }
    #pragma unroll
    for (int j = 0; j < 2; ++j) {
      bf16x8 v;
      v[0] = (short)f2bf(fb[2*j].x);   v[1] = (short)f2bf(fb[2*j].y);
      v[2] = (short)f2bf(fb[2*j].z);   v[3] = (short)f2bf(fb[2*j].w);
      v[4] = (short)f2bf(fb[2*j+1].x); v[5] = (short)f2bf(fb[2*j+1].y);
      v[6] = (short)f2bf(fb[2*j+1].z); v[7] = (short)f2bf(fb[2*j+1].w);
      int slot = (koffB >> 3) + j;
      *(bf16x8*)((char*)Bs + rowB * 128 + ((slot ^ (rowB & 7)) << 4)) = v;
    }
    __syncthreads();
    #pragma unroll
    for (int kk = 0; kk < 2; ++kk) {
      bf16x8 a0 = *(bf16x8*)((char*)As + aoff[kk][0]);
      bf16x8 a1 = *(bf16x8*)((char*)As + aoff[kk][1]);
      bf16x8 b0 = *(bf16x8*)((char*)Bs + boff[kk][0]);
      bf16x8 b1 = *(bf16x8*)((char*)Bs + boff[kk][1]);
      bf16x8 b2 = *(bf16x8*)((char*)Bs + boff[kk][2]);
      bf16x8 b3 = *(bf16x8*)((char*)Bs + boff[kk][3]);
      acc[0][0] = __builtin_amdgcn_mfma_f32_16x16x32_bf16(a0, b0, acc[0][0], 0, 0, 0);
      acc[0][1] = __builtin_amdgcn_mfma_f32_16x16x32_bf16(a0, b1, acc[0][1], 0, 0, 0);
      acc[0][2] = __builtin_amdgcn_mfma_f32_16x16x32_bf16(a0, b2, acc[0][2], 0, 0, 0);
      acc[0][3] = __builtin_amdgcn_mfma_f32_16x16x32_bf16(a0, b3, acc[0][3], 0, 0, 0);
      acc[1][0] = __builtin_amdgcn_mfma_f32_16x16x32_bf16(a1, b0, acc[1][0], 0, 0, 0);
      acc[1][1] = __builtin_amdgcn_mfma_f32_16x16x32_bf16(a1, b1, acc[1][1], 0, 0, 0);
      acc[1][2] = __builtin_amdgcn_mfma_f32_16x16x32_bf16(a1, b2, acc[1][2], 0, 0, 0);
      acc[1][3] = __builtin_amdgcn_mfma_f32_16x16x32_bf16(a1, b3, acc[1][3], 0, 0, 0);
    }
  }

  float* O = out + outOff;
  #pragma unroll
  for (int mi = 0; mi < 2; ++mi) {
    int row = wav * 32 + mi * 16 + kb * 4;
    #pragma unroll
    for (int ni = 0; ni < 4; ++ni) {
      int cl = n0 + ni * 16 + r;
      if (cl < 200) {
        float bv = bi[cl];
        #pragma unroll
        for (int g2 = 0; g2 < 4; ++g2)
          O[(size_t)(row + g2) * 200 + cl] = acc[mi][ni][g2] + bv;
      }
    }
  }
}

// ---------------------------------------------------------------------------
extern "C" void kernel_launch(void* const* d_in, const int* in_sizes, int n_in,
                              void* d_out, int out_size, void* d_ws, size_t ws_size,
                              hipStream_t stream) {
  const float* x      = (const float*)d_in[0];
  const float* g_bn_g = (const float*)d_in[1];
  const float* g_bn_b = (const float*)d_in[2];
  const float* g_w    = (const float*)d_in[3];
  const float* g_b    = (const float*)d_in[4];
  const float* e_w    = (const float*)d_in[5];
  const float* e_b    = (const float*)d_in[6];
  const float* e_g    = (const float*)d_in[7];
  const float* e_bb   = (const float*)d_in[8];
  const float* hl_g1  = (const float*)d_in[9];
  const float* hl_b1  = (const float*)d_in[10];
  const float* hl_w1  = (const float*)d_in[11];
  const float* hl_bi1 = (const float*)d_in[12];
  const float* hl_g2  = (const float*)d_in[13];
  const float* hl_b2  = (const float*)d_in[14];
  const float* hl_w2  = (const float*)d_in[15];
  const float* hl_bi2 = (const float*)d_in[16];
  const float* hh_g1  = (const float*)d_in[17];
  const float* hh_b1  = (const float*)d_in[18];
  const float* hh_w1  = (const float*)d_in[19];
  const float* hh_bi1 = (const float*)d_in[20];
  const float* hh_g2  = (const float*)d_in[21];
  const float* hh_b2  = (const float*)d_in[22];
  const float* hh_w2  = (const float*)d_in[23];
  const float* hh_bi2 = (const float*)d_in[24];
  const float* hf_g1  = (const float*)d_in[25];
  const float* hf_b1  = (const float*)d_in[26];
  const float* hf_w1  = (const float*)d_in[27];
  const float* hf_bi1 = (const float*)d_in[28];
  const float* hf_g2  = (const float*)d_in[29];
  const float* hf_b2  = (const float*)d_in[30];
  const float* hf_w2  = (const float*)d_in[31];
  const float* hf_bi2 = (const float*)d_in[32];
  float* out = (float*)d_out;

  float* W = (float*)d_ws;
  const size_t BC = (size_t)B_DIM * C_DIM;   // 262144
  float* mp   = W;
  float* ms   = mp + BC;
  float* pool = ms + BC * 4;
  float* xl   = pool + BC;
  float* a2_l = xl + BC;
  float* a2_h = a2_l + 128 * 512;
  float* a2_f = a2_h + 128 * 512;
  float* st   = a2_f + 128 * 1024;
  float* mean_mp = st;           float* rstd_mp = st + 2048;
  float* s_h  = st + 2 * 2048;   float* t_h  = st + 3 * 2048;
  float* sf2  = st + 4 * 2048;   float* tf2  = st + 5 * 2048;
  float* s_l  = st + 6 * 2048;   float* t_l  = st + 7 * 2048;
  float* sf1  = st + 8 * 2048;   float* tf1  = st + 9 * 2048;
  float* P_e  = st + 10 * 2048;                 // 8 x 262144
  float* P_l2 = P_e + 8 * BC;                   // 8 x 65536
  float* P_hh = P_l2 + (size_t)8 * 65536;       // 8 x 65536
  float* P_f  = P_hh + (size_t)8 * 65536;       // 8 x 131072

  pool_max_kernel<<<16384, 256, 0, stream>>>(x, mp, ms);

  statsmp_kernel<<<128, 256, 0, stream>>>(mp, hh_g1, hh_b1, hf_g1, hf_b1,
                                          mean_mp, rstd_mp, s_h, t_h, sf2, tf2);

  gate_select_kernel<<<128, 256, 0, stream>>>(mp, mean_mp, rstd_mp, g_bn_g, g_bn_b,
                                              g_w, g_b, ms, pool);

  gemm_e_mfma_kernel<<<dim3(32, 8), 256, 0, stream>>>(pool, e_w, P_e);

  expert_fused_kernel<<<128, 256, 0, stream>>>(P_e, e_b, e_g, e_bb,
                                               hl_g1, hl_b1, hf_g1, hf_b1,
                                               xl, s_l, t_l, sf1, tf1);

  gemm_w1_mfma_kernel<<<dim3(32, 8), 256, 0, stream>>>(
      xl, mp, s_l, t_l, s_h, t_h, sf1, tf1, sf2, tf2,
      hl_w1, hh_w1, hf_w1, P_l2, P_hh, P_f);

  heads_fused_kernel<<<128, 256, 0, stream>>>(
      P_l2, P_hh, P_f, hl_bi1, hh_bi1, hf_bi1,
      hl_g2, hl_b2, hh_g2, hh_b2, hf_g2, hf_b2,
      a2_l, a2_h, a2_f);

  gemm_w2_mfma_kernel<<<12, 256, 0, stream>>>(
      a2_l, a2_h, a2_f, hl_w2, hh_w2, hf_w2,
      hl_bi2, hh_bi2, hf_bi2, out);
}

// Round 9
// 147.456 us; speedup vs baseline: 1.0660x; 1.0660x over previous
//
#include <hip/hip_runtime.h>
#include <math.h>

#define B_DIM 128
#define C_DIM 2048
#define HW2   196

typedef __attribute__((ext_vector_type(8))) short bf16x8;
typedef __attribute__((ext_vector_type(4))) float f32x4;

__device__ __forceinline__ unsigned short f2bf(float f) {
  unsigned u = __float_as_uint(f);
  u += 0x7FFFu + ((u >> 16) & 1u);     // RNE
  return (unsigned short)(u >> 16);
}

// ---------------------------------------------------------------------------
// K1: per-(b,c) 14x14 tile -> global max (mp) + 4-scale adaptive avg-pool max.
// Register-resident separable pooling. (Plain float4 loads — NT regressed R8.)
// ---------------------------------------------------------------------------
__global__ __launch_bounds__(256) void pool_max_kernel(
    const float* __restrict__ x, float* __restrict__ mp, float* __restrict__ ms) {
  __shared__ float lds[4][4][208];
  const int tid  = threadIdx.x;
  const int w    = tid >> 6;
  const int lane = tid & 63;
  const int g    = lane >> 4;
  const int c    = lane & 15;
  const size_t waveBase = (size_t)blockIdx.x * 16 + w * 4;

  const float* src = x + waveBase * HW2;
  #pragma unroll
  for (int j = 0; j < 4; ++j) {
    int f = lane + 64 * j;
    if (f < 196) {
      int t = (f * 669) >> 15;       // f / 49
      float4 v = *(const float4*)(src + f * 4);
      *(float4*)&lds[w][t][(f - 49 * t) * 4] = v;
    }
  }

  float xv[14];
  const float* col = &lds[w][g][c];
  #pragma unroll
  for (int r = 0; r < 14; ++r) xv[r] = col[r * 14];

  float cmax = (c < 14) ? xv[0] : -INFINITY;
  #pragma unroll
  for (int r = 1; r < 14; ++r) if (c < 14) cmax = fmaxf(cmax, xv[r]);
  #pragma unroll
  for (int off = 8; off > 0; off >>= 1) cmax = fmaxf(cmax, __shfl_xor(cmax, off));

  float P[15];
  P[0] = 0.f;
  #pragma unroll
  for (int r = 0; r < 14; ++r) P[r + 1] = P[r] + xv[r];

  float sm0, sm1, sm2, sm3;

  { // k=4
    constexpr int rs[4] = {0, 3, 7, 10}, re[4] = {4, 7, 11, 14};
    const bool valid = (0x489u >> c) & 1;
    float vmax = -INFINITY;
    #pragma unroll
    for (int i = 0; i < 4; ++i) {
      float v  = P[re[i]] - P[rs[i]];
      float w2 = v + __shfl_down(v, 1);
      float w4 = w2 + __shfl_down(w2, 2);
      vmax = fmaxf(vmax, valid ? w4 : -INFINITY);
    }
    #pragma unroll
    for (int off = 8; off > 0; off >>= 1) vmax = fmaxf(vmax, __shfl_xor(vmax, off));
    sm0 = vmax * 0.0625f;
  }
  { // k=5
    constexpr int rs[5] = {0, 2, 5, 8, 11}, re[5] = {3, 6, 9, 12, 14};
    constexpr float srl[5] = {1.f/3.f, 0.25f, 0.25f, 0.25f, 1.f/3.f};
    const bool valid = (0x925u >> c) & 1;
    const bool is3   = (0x801u >> c) & 1;
    const float invc = is3 ? (1.f/3.f) : 0.25f;
    float vmax = -INFINITY;
    #pragma unroll
    for (int i = 0; i < 5; ++i) {
      float v  = P[re[i]] - P[rs[i]];
      float d1 = __shfl_down(v, 1);
      float d2 = __shfl_down(v, 2);
      float w2 = v + d1;
      float w3 = w2 + d2;
      float w4 = w2 + __shfl_down(w2, 2);
      float wv = (is3 ? w3 : w4) * invc * srl[i];
      vmax = fmaxf(vmax, valid ? wv : -INFINITY);
    }
    #pragma unroll
    for (int off = 8; off > 0; off >>= 1) vmax = fmaxf(vmax, __shfl_xor(vmax, off));
    sm1 = vmax;
  }
  { // k=7
    constexpr int rs[7] = {0, 2, 4, 6, 8, 10, 12};
    const bool valid = (0x1555u >> c) & 1;
    float vmax = -INFINITY;
    #pragma unroll
    for (int i = 0; i < 7; ++i) {
      float v  = P[rs[i] + 2] - P[rs[i]];
      float w2 = v + __shfl_down(v, 1);
      vmax = fmaxf(vmax, valid ? w2 : -INFINITY);
    }
    #pragma unroll
    for (int off = 8; off > 0; off >>= 1) vmax = fmaxf(vmax, __shfl_xor(vmax, off));
    sm2 = vmax * 0.25f;
  }
  { // k=11
    constexpr int rs[11] = {0, 1, 2, 3, 5, 6, 7, 8, 10, 11, 12};
    constexpr int re[11] = {2, 3, 4, 6, 7, 8, 9, 11, 12, 13, 14};
    constexpr float srl[11] = {0.5f, 0.5f, 0.5f, 1.f/3.f, 0.5f, 0.5f, 0.5f,
                               1.f/3.f, 0.5f, 0.5f, 0.5f};
    const bool valid = (0x1DEFu >> c) & 1;
    const bool is3   = (0x108u >> c) & 1;
    const float invc = is3 ? (1.f/3.f) : 0.5f;
    float vmax = -INFINITY;
    #pragma unroll
    for (int i = 0; i < 11; ++i) {
      float v  = P[re[i]] - P[rs[i]];
      float d1 = __shfl_down(v, 1);
      float d2 = __shfl_down(v, 2);
      float w2 = v + d1;
      float w3 = w2 + d2;
      float wv = (is3 ? w3 : w2) * invc * srl[i];
      vmax = fmaxf(vmax, valid ? wv : -INFINITY);
    }
    #pragma unroll
    for (int off = 8; off > 0; off >>= 1) vmax = fmaxf(vmax, __shfl_xor(vmax, off));
    sm3 = vmax;
  }

  if (c == 0) {
    size_t T = waveBase + g;
    mp[T] = cmax;
    *(float4*)&ms[T * 4] = make_float4(sm0, sm1, sm2, sm3);
  }
}

// ---------------------------------------------------------------------------
// K2: mp column stats + affine params (hh head, hf second half)
// ---------------------------------------------------------------------------
__global__ __launch_bounds__(256) void statsmp_kernel(
    const float* __restrict__ mp,
    const float* __restrict__ hh_g1, const float* __restrict__ hh_b1,
    const float* __restrict__ hf_g1, const float* __restrict__ hf_b1,
    float* __restrict__ mean_mp, float* __restrict__ rstd_mp,
    float* __restrict__ s_h, float* __restrict__ t_h,
    float* __restrict__ sf2, float* __restrict__ tf2) {
  const int ci = threadIdx.x & 15;
  const int g  = threadIdx.x >> 4;
  const int c  = blockIdx.x * 16 + ci;
  float s = 0.f, q = 0.f;
  #pragma unroll
  for (int r = 0; r < 8; ++r) {
    float v = mp[(size_t)(g * 8 + r) * C_DIM + c];
    s += v; q += v * v;
  }
  __shared__ float ss[16][16], qq[16][16];
  ss[g][ci] = s; qq[g][ci] = q;
  __syncthreads();
  if (g == 0) {
    float S = 0.f, Q = 0.f;
    #pragma unroll
    for (int j = 0; j < 16; ++j) { S += ss[j][ci]; Q += qq[j][ci]; }
    float m = S * (1.f / B_DIM);
    float var = Q * (1.f / B_DIM) - m * m;
    if (var < 0.f) var = 0.f;
    float r = rsqrtf(var + 1e-5f);
    mean_mp[c] = m; rstd_mp[c] = r;
    float a = r * hh_g1[c];        s_h[c] = a; t_h[c] = hh_b1[c] - m * a;
    float b = r * hf_g1[2048 + c]; sf2[c] = b; tf2[c] = hf_b1[2048 + c] - m * b;
  }
}

// ---------------------------------------------------------------------------
// K3: gate (BN+ELU+linear+argmax) fused with gated scale select -> pool
// ---------------------------------------------------------------------------
__global__ void gate_select_kernel(
    const float* __restrict__ mp,
    const float* __restrict__ mean, const float* __restrict__ rstd,
    const float* __restrict__ gg, const float* __restrict__ gb,
    const float* __restrict__ gw, const float* __restrict__ gbias,
    const float* __restrict__ ms, float* __restrict__ pool) {
  const int b = blockIdx.x;
  const int t = threadIdx.x;
  float s0 = 0.f, s1 = 0.f, s2 = 0.f, s3 = 0.f;
  for (int c = t; c < C_DIM; c += 256) {
    float v = mp[(size_t)b * C_DIM + c];
    float xn = (v - mean[c]) * rstd[c] * gg[c] + gb[c];
    float e = xn > 0.f ? xn : expm1f(xn);
    s0 += e * gw[c];
    s1 += e * gw[C_DIM + c];
    s2 += e * gw[2 * C_DIM + c];
    s3 += e * gw[3 * C_DIM + c];
  }
  __shared__ float red[4][256];
  __shared__ int ssel;
  red[0][t] = s0; red[1][t] = s1; red[2][t] = s2; red[3][t] = s3;
  __syncthreads();
  for (int st = 128; st > 0; st >>= 1) {
    if (t < st) {
      red[0][t] += red[0][t + st];
      red[1][t] += red[1][t + st];
      red[2][t] += red[2][t + st];
      red[3][t] += red[3][t + st];
    }
    __syncthreads();
  }
  if (t == 0) {
    float best = red[0][0] + gbias[0];
    int bi = 0;
    for (int j = 1; j < 4; ++j) {
      float l = red[j][0] + gbias[j];
      if (l > best) { best = l; bi = j; }
    }
    ssel = bi;
  }
  __syncthreads();
  const int sel = ssel;
  for (int c = t; c < C_DIM; c += 256)
    pool[(size_t)b * C_DIM + c] = ms[((size_t)b * C_DIM + c) * 4 + sel];
}

// ---------------------------------------------------------------------------
// K4: expert GEMM, bf16 MFMA. BM=128 BN=64 BK=64, grid (32, z=8), Kc=256.
// ---------------------------------------------------------------------------
__global__ __launch_bounds__(256) void gemm_e_mfma_kernel(
    const float* __restrict__ A, const float* __restrict__ W,
    float* __restrict__ P) {
  __shared__ __align__(16) short As[128 * 64];
  __shared__ __align__(16) short Bs[64 * 64];
  const int t = threadIdx.x;
  const int n0 = blockIdx.x << 6;
  const int kbeg = blockIdx.y << 8;          // Kc = 256

  const int rowA = t >> 1, koffA = (t & 1) << 5;
  const int rowB = t >> 2, koffB = (t & 3) << 4;

  const int lane = t & 63, wav = t >> 6;
  const int r = lane & 15, kb = lane >> 4;
  int aoff[2][2], boff[2][4];
  #pragma unroll
  for (int kk = 0; kk < 2; ++kk) {
    #pragma unroll
    for (int mi = 0; mi < 2; ++mi) {
      int row = wav * 32 + mi * 16 + r;
      aoff[kk][mi] = row * 128 + ((((kk << 2) + kb) ^ (row & 7)) << 4);
    }
    #pragma unroll
    for (int ni = 0; ni < 4; ++ni) {
      int cl = ni * 16 + r;
      boff[kk][ni] = cl * 128 + ((((kk << 2) + kb) ^ (cl & 7)) << 4);
    }
  }

  f32x4 acc[2][4];
  #pragma unroll
  for (int mi = 0; mi < 2; ++mi)
    #pragma unroll
    for (int ni = 0; ni < 4; ++ni)
      acc[mi][ni] = (f32x4){0.f, 0.f, 0.f, 0.f};

  for (int kt = 0; kt < 256; kt += 64) {
    const int kg = kbeg + kt;
    const float4* ap = (const float4*)&A[(size_t)rowA * 2048 + kg + koffA];
    const float4* bp = (const float4*)&W[(size_t)(n0 + rowB) * 2048 + kg + koffB];
    float4 fa[8], fb[4];
    #pragma unroll
    for (int j = 0; j < 8; ++j) fa[j] = ap[j];
    #pragma unroll
    for (int j = 0; j < 4; ++j) fb[j] = bp[j];
    __syncthreads();
    #pragma unroll
    for (int j = 0; j < 4; ++j) {
      bf16x8 v;
      v[0] = (short)f2bf(fa[2*j].x);   v[1] = (short)f2bf(fa[2*j].y);
      v[2] = (short)f2bf(fa[2*j].z);   v[3] = (short)f2bf(fa[2*j].w);
      v[4] = (short)f2bf(fa[2*j+1].x); v[5] = (short)f2bf(fa[2*j+1].y);
      v[6] = (short)f2bf(fa[2*j+1].z); v[7] = (short)f2bf(fa[2*j+1].w);
      int slot = (koffA >> 3) + j;
      *(bf16x8*)((char*)As + rowA * 128 + ((slot ^ (rowA & 7)) << 4)) = v;
    }
    #pragma unroll
    for (int j = 0; j < 2; ++j) {
      bf16x8 v;
      v[0] = (short)f2bf(fb[2*j].x);   v[1] = (short)f2bf(fb[2*j].y);
      v[2] = (short)f2bf(fb[2*j].z);   v[3] = (short)f2bf(fb[2*j].w);
      v[4] = (short)f2bf(fb[2*j+1].x); v[5] = (short)f2bf(fb[2*j+1].y);
      v[6] = (short)f2bf(fb[2*j+1].z); v[7] = (short)f2bf(fb[2*j+1].w);
      int slot = (koffB >> 3) + j;
      *(bf16x8*)((char*)Bs + rowB * 128 + ((slot ^ (rowB & 7)) << 4)) = v;
    }
    __syncthreads();
    #pragma unroll
    for (int kk = 0; kk < 2; ++kk) {
      bf16x8 a0 = *(bf16x8*)((char*)As + aoff[kk][0]);
      bf16x8 a1 = *(bf16x8*)((char*)As + aoff[kk][1]);
      bf16x8 b0 = *(bf16x8*)((char*)Bs + boff[kk][0]);
      bf16x8 b1 = *(bf16x8*)((char*)Bs + boff[kk][1]);
      bf16x8 b2 = *(bf16x8*)((char*)Bs + boff[kk][2]);
      bf16x8 b3 = *(bf16x8*)((char*)Bs + boff[kk][3]);
      acc[0][0] = __builtin_amdgcn_mfma_f32_16x16x32_bf16(a0, b0, acc[0][0], 0, 0, 0);
      acc[0][1] = __builtin_amdgcn_mfma_f32_16x16x32_bf16(a0, b1, acc[0][1], 0, 0, 0);
      acc[0][2] = __builtin_amdgcn_mfma_f32_16x16x32_bf16(a0, b2, acc[0][2], 0, 0, 0);
      acc[0][3] = __builtin_amdgcn_mfma_f32_16x16x32_bf16(a0, b3, acc[0][3], 0, 0, 0);
      acc[1][0] = __builtin_amdgcn_mfma_f32_16x16x32_bf16(a1, b0, acc[1][0], 0, 0, 0);
      acc[1][1] = __builtin_amdgcn_mfma_f32_16x16x32_bf16(a1, b1, acc[1][1], 0, 0, 0);
      acc[1][2] = __builtin_amdgcn_mfma_f32_16x16x32_bf16(a1, b2, acc[1][2], 0, 0, 0);
      acc[1][3] = __builtin_amdgcn_mfma_f32_16x16x32_bf16(a1, b3, acc[1][3], 0, 0, 0);
    }
  }

  float* Pz = P + ((size_t)blockIdx.y << 18);
  #pragma unroll
  for (int mi = 0; mi < 2; ++mi) {
    int row = wav * 32 + mi * 16 + kb * 4;
    #pragma unroll
    for (int ni = 0; ni < 4; ++ni) {
      int cl = n0 + ni * 16 + r;
      #pragma unroll
      for (int g2 = 0; g2 < 4; ++g2)
        Pz[(size_t)(row + g2) * 2048 + cl] = acc[mi][ni][g2];
    }
  }
}

// ---------------------------------------------------------------------------
// K5: expert fused epilogue (reduce 8 partials + bias -> BN -> relu -> stats)
// ---------------------------------------------------------------------------
__global__ __launch_bounds__(256) void expert_fused_kernel(
    const float* __restrict__ Pe, const float* __restrict__ e_b,
    const float* __restrict__ e_g, const float* __restrict__ e_bb,
    const float* __restrict__ hl_g1, const float* __restrict__ hl_b1,
    const float* __restrict__ hf_g1, const float* __restrict__ hf_b1,
    float* __restrict__ xl,
    float* __restrict__ s_l, float* __restrict__ t_l,
    float* __restrict__ sf1, float* __restrict__ tf1) {
  const int ci = threadIdx.x & 15;
  const int g  = threadIdx.x >> 4;
  const int c  = blockIdx.x * 16 + ci;
  float v[8];
  float s = 0.f, q = 0.f;
  const float bias = e_b[c];
  #pragma unroll
  for (int r = 0; r < 8; ++r) {
    const size_t row = g * 8 + r;
    float acc = bias;
    #pragma unroll
    for (int z = 0; z < 8; ++z)
      acc += Pe[((size_t)z << 18) + row * 2048 + c];
    v[r] = acc; s += acc; q += acc * acc;
  }
  __shared__ float ss[16][16], qq[16][16];
  __shared__ float sm[16], sr[16];
  ss[g][ci] = s; qq[g][ci] = q;
  __syncthreads();
  if (g == 0) {
    float S = 0.f, Q = 0.f;
    #pragma unroll
    for (int j = 0; j < 16; ++j) { S += ss[j][ci]; Q += qq[j][ci]; }
    float m = S * (1.f / B_DIM);
    float var = Q * (1.f / B_DIM) - m * m;
    if (var < 0.f) var = 0.f;
    sm[ci] = m; sr[ci] = rsqrtf(var + 1e-5f);
  }
  __syncthreads();
  const float m = sm[ci], rst = sr[ci];
  const float eg = e_g[c], eb2 = e_bb[c];
  float s2 = 0.f, q2 = 0.f;
  #pragma unroll
  for (int r = 0; r < 8; ++r) {
    float xv = fmaxf((v[r] - m) * rst * eg + eb2, 0.f);
    xl[(size_t)(g * 8 + r) * 2048 + c] = xv;
    s2 += xv; q2 += xv * xv;
  }
  __syncthreads();
  ss[g][ci] = s2; qq[g][ci] = q2;
  __syncthreads();
  if (g == 0) {
    float S = 0.f, Q = 0.f;
    #pragma unroll
    for (int j = 0; j < 16; ++j) { S += ss[j][ci]; Q += qq[j][ci]; }
    float mm = S * (1.f / B_DIM);
    float var = Q * (1.f / B_DIM) - mm * mm;
    if (var < 0.f) var = 0.f;
    float rr = rsqrtf(var + 1e-5f);
    float a = rr * hl_g1[c]; s_l[c] = a; t_l[c] = hl_b1[c] - mm * a;
    float b = rr * hf_g1[c]; sf1[c] = b; tf1[c] = hf_b1[c] - mm * b;
  }
}

// ---------------------------------------------------------------------------
// K6: combined head-linear1 GEMM, bf16 MFMA, BN1 affine folded into A staging.
// grid (32, 16) — R7 config (2 blocks/CU hides barrier drain; R8's (32,8) regressed).
// jobs: [0,8)=hl, [8,16)=hh, [16,32)=hf. Kc: l/h=128, f=256.
// ---------------------------------------------------------------------------
__global__ __launch_bounds__(256) void gemm_w1_mfma_kernel(
    const float* __restrict__ xl, const float* __restrict__ mp,
    const float* __restrict__ s_l, const float* __restrict__ t_l,
    const float* __restrict__ s_h, const float* __restrict__ t_h,
    const float* __restrict__ sf1, const float* __restrict__ tf1,
    const float* __restrict__ sf2, const float* __restrict__ tf2,
    const float* __restrict__ hl_w1, const float* __restrict__ hh_w1,
    const float* __restrict__ hf_w1,
    float* __restrict__ P_l, float* __restrict__ P_h, float* __restrict__ P_f) {
  __shared__ __align__(16) short As[128 * 64];
  __shared__ __align__(16) short Bs[64 * 64];
  const int jx = blockIdx.x;
  const int z  = blockIdx.y;
  const float *A, *S, *T, *Wt;
  float* P;
  int N, Kdim, n0, kA0, kW0, Kc;
  if (jx < 8) {
    N = 512; Kdim = 2048; Kc = 128; Wt = hl_w1; n0 = jx << 6;
    kW0 = z * 128; kA0 = kW0; A = xl; S = s_l; T = t_l;
    P = P_l + ((size_t)z << 16);
  } else if (jx < 16) {
    N = 512; Kdim = 2048; Kc = 128; Wt = hh_w1; n0 = (jx - 8) << 6;
    kW0 = z * 128; kA0 = kW0; A = mp; S = s_h; T = t_h;
    P = P_h + ((size_t)z << 16);
  } else {
    N = 1024; Kdim = 4096; Kc = 256; Wt = hf_w1; n0 = (jx - 16) << 6;
    kW0 = z * 256;
    if (kW0 >= 2048) { A = mp; S = sf2; T = tf2; kA0 = kW0 - 2048; }
    else             { A = xl; S = sf1; T = tf1; kA0 = kW0; }
    P = P_f + ((size_t)z << 17);
  }
  const int t = threadIdx.x;
  const int rowA = t >> 1, koffA = (t & 1) << 5;
  const int rowB = t >> 2, koffB = (t & 3) << 4;

  const int lane = t & 63, wav = t >> 6;
  const int r = lane & 15, kb = lane >> 4;
  int aoff[2][2], boff[2][4];
  #pragma unroll
  for (int kk = 0; kk < 2; ++kk) {
    #pragma unroll
    for (int mi = 0; mi < 2; ++mi) {
      int row = wav * 32 + mi * 16 + r;
      aoff[kk][mi] = row * 128 + ((((kk << 2) + kb) ^ (row & 7)) << 4);
    }
    #pragma unroll
    for (int ni = 0; ni < 4; ++ni) {
      int cl = ni * 16 + r;
      boff[kk][ni] = cl * 128 + ((((kk << 2) + kb) ^ (cl & 7)) << 4);
    }
  }

  f32x4 acc[2][4];
  #pragma unroll
  for (int mi = 0; mi < 2; ++mi)
    #pragma unroll
    for (int ni = 0; ni < 4; ++ni)
      acc[mi][ni] = (f32x4){0.f, 0.f, 0.f, 0.f};

  for (int kt = 0; kt < Kc; kt += 64) {
    const int ka = kA0 + kt + koffA;
    const float4* ap = (const float4*)&A[(size_t)rowA * 2048 + ka];
    const float4* sp = (const float4*)&S[ka];
    const float4* tp = (const float4*)&T[ka];
    const float4* bp = (const float4*)&Wt[(size_t)(n0 + rowB) * Kdim + kW0 + kt + koffB];
    float4 fa[8], fb[4];
    #pragma unroll
    for (int j = 0; j < 8; ++j) fa[j] = ap[j];
    #pragma unroll
    for (int j = 0; j < 8; ++j) {
      float4 s4 = sp[j], t4 = tp[j];
      fa[j].x = fmaf(fa[j].x, s4.x, t4.x);
      fa[j].y = fmaf(fa[j].y, s4.y, t4.y);
      fa[j].z = fmaf(fa[j].z, s4.z, t4.z);
      fa[j].w = fmaf(fa[j].w, s4.w, t4.w);
    }
    #pragma unroll
    for (int j = 0; j < 4; ++j) fb[j] = bp[j];
    __syncthreads();
    #pragma unroll
    for (int j = 0; j < 4; ++j) {
      bf16x8 v;
      v[0] = (short)f2bf(fa[2*j].x);   v[1] = (short)f2bf(fa[2*j].y);
      v[2] = (short)f2bf(fa[2*j].z);   v[3] = (short)f2bf(fa[2*j].w);
      v[4] = (short)f2bf(fa[2*j+1].x); v[5] = (short)f2bf(fa[2*j+1].y);
      v[6] = (short)f2bf(fa[2*j+1].z); v[7] = (short)f2bf(fa[2*j+1].w);
      int slot = (koffA >> 3) + j;
      *(bf16x8*)((char*)As + rowA * 128 + ((slot ^ (rowA & 7)) << 4)) = v;
    }
    #pragma unroll
    for (int j = 0; j < 2; ++j) {
      bf16x8 v;
      v[0] = (short)f2bf(fb[2*j].x);   v[1] = (short)f2bf(fb[2*j].y);
      v[2] = (short)f2bf(fb[2*j].z);   v[3] = (short)f2bf(fb[2*j].w);
      v[4] = (short)f2bf(fb[2*j+1].x); v[5] = (short)f2bf(fb[2*j+1].y);
      v[6] = (short)f2bf(fb[2*j+1].z); v[7] = (short)f2bf(fb[2*j+1].w);
      int slot = (koffB >> 3) + j;
      *(bf16x8*)((char*)Bs + rowB * 128 + ((slot ^ (rowB & 7)) << 4)) = v;
    }
    __syncthreads();
    #pragma unroll
    for (int kk = 0; kk < 2; ++kk) {
      bf16x8 a0 = *(bf16x8*)((char*)As + aoff[kk][0]);
      bf16x8 a1 = *(bf16x8*)((char*)As + aoff[kk][1]);
      bf16x8 b0 = *(bf16x8*)((char*)Bs + boff[kk][0]);
      bf16x8 b1 = *(bf16x8*)((char*)Bs + boff[kk][1]);
      bf16x8 b2 = *(bf16x8*)((char*)Bs + boff[kk][2]);
      bf16x8 b3 = *(bf16x8*)((char*)Bs + boff[kk][3]);
      acc[0][0] = __builtin_amdgcn_mfma_f32_16x16x32_bf16(a0, b0, acc[0][0], 0, 0, 0);
      acc[0][1] = __builtin_amdgcn_mfma_f32_16x16x32_bf16(a0, b1, acc[0][1], 0, 0, 0);
      acc[0][2] = __builtin_amdgcn_mfma_f32_16x16x32_bf16(a0, b2, acc[0][2], 0, 0, 0);
      acc[0][3] = __builtin_amdgcn_mfma_f32_16x16x32_bf16(a0, b3, acc[0][3], 0, 0, 0);
      acc[1][0] = __builtin_amdgcn_mfma_f32_16x16x32_bf16(a1, b0, acc[1][0], 0, 0, 0);
      acc[1][1] = __builtin_amdgcn_mfma_f32_16x16x32_bf16(a1, b1, acc[1][1], 0, 0, 0);
      acc[1][2] = __builtin_amdgcn_mfma_f32_16x16x32_bf16(a1, b2, acc[1][2], 0, 0, 0);
      acc[1][3] = __builtin_amdgcn_mfma_f32_16x16x32_bf16(a1, b3, acc[1][3], 0, 0, 0);
    }
  }

  #pragma unroll
  for (int mi = 0; mi < 2; ++mi) {
    int row = wav * 32 + mi * 16 + kb * 4;
    #pragma unroll
    for (int ni = 0; ni < 4; ++ni) {
      int cl = n0 + ni * 16 + r;
      #pragma unroll
      for (int g2 = 0; g2 < 4; ++g2)
        P[(size_t)(row + g2) * N + cl] = acc[mi][ni][g2];
    }
  }
}

// ---------------------------------------------------------------------------
// K7: heads fused epilogue (reduce 16 partial slices + bias -> BN -> ELU)
// ---------------------------------------------------------------------------
__global__ __launch_bounds__(256) void heads_fused_kernel(
    const float* __restrict__ P_l, const float* __restrict__ P_h,
    const float* __restrict__ P_f,
    const float* __restrict__ bl1, const float* __restrict__ bh1,
    const float* __restrict__ bf1,
    const float* __restrict__ g2l, const float* __restrict__ b2l,
    const float* __restrict__ g2h, const float* __restrict__ b2h,
    const float* __restrict__ g2f, const float* __restrict__ b2f,
    float* __restrict__ a2_l, float* __restrict__ a2_h, float* __restrict__ a2_f) {
  const int ci = threadIdx.x & 15;
  const int g  = threadIdx.x >> 4;
  const int cj = blockIdx.x * 16 + ci;
  const float *P, *bi, *g2, *b2;
  float* out;
  int N, cc;
  if (cj < 512)       { P = P_l; bi = bl1; g2 = g2l; b2 = b2l; out = a2_l; N = 512;  cc = cj; }
  else if (cj < 1024) { P = P_h; bi = bh1; g2 = g2h; b2 = b2h; out = a2_h; N = 512;  cc = cj - 512; }
  else                { P = P_f; bi = bf1; g2 = g2f; b2 = b2f; out = a2_f; N = 1024; cc = cj - 1024; }
  const size_t sstride = (size_t)N * 128;
  float v[8];
  float s = 0.f, q = 0.f;
  const float bias = bi[cc];
  #pragma unroll
  for (int r = 0; r < 8; ++r) {
    const size_t row = g * 8 + r;
    float acc = bias;
    #pragma unroll
    for (int z = 0; z < 16; ++z)
      acc += P[(size_t)z * sstride + row * N + cc];
    v[r] = acc; s += acc; q += acc * acc;
  }
  __shared__ float ss[16][16], qq[16][16];
  __shared__ float sm[16], sr[16];
  ss[g][ci] = s; qq[g][ci] = q;
  __syncthreads();
  if (g == 0) {
    float S = 0.f, Q = 0.f;
    #pragma unroll
    for (int j = 0; j < 16; ++j) { S += ss[j][ci]; Q += qq[j][ci]; }
    float m = S * (1.f / B_DIM);
    float var = Q * (1.f / B_DIM) - m * m;
    if (var < 0.f) var = 0.f;
    sm[ci] = m; sr[ci] = rsqrtf(var + 1e-5f);
  }
  __syncthreads();
  const float m = sm[ci], rr = sr[ci];
  const float gg = g2[cc], bb = b2[cc];
  #pragma unroll
  for (int r = 0; r < 8; ++r) {
    float xn = (v[r] - m) * rr * gg + bb;
    out[(size_t)(g * 8 + r) * N + cc] = xn > 0.f ? xn : expm1f(xn);
  }
}

// ---------------------------------------------------------------------------
// K8: head-linear2 bf16 MFMA, full K, direct out+bias. BM=64, grid (12, 2).
// jx<4: low (K=512), jx<8: high (K=512), else: full (K=1024). n0=(jx&3)*64.
// ---------------------------------------------------------------------------
__global__ __launch_bounds__(256) void gemm_w2_mfma_kernel(
    const float* __restrict__ a2_l, const float* __restrict__ a2_h,
    const float* __restrict__ a2_f,
    const float* __restrict__ hl_w2, const float* __restrict__ hh_w2,
    const float* __restrict__ hf_w2,
    const float* __restrict__ bl2, const float* __restrict__ bh2,
    const float* __restrict__ bf2,
    float* __restrict__ out) {
  __shared__ __align__(16) short As[64 * 64];
  __shared__ __align__(16) short Bs[64 * 64];
  const int jx = blockIdx.x;
  const int m0 = blockIdx.y << 6;
  const float *A, *Wt, *bi;
  int K, outOff;
  if (jx < 4)      { A = a2_l; Wt = hl_w2; bi = bl2; K = 512;  outOff = 0; }
  else if (jx < 8) { A = a2_h; Wt = hh_w2; bi = bh2; K = 512;  outOff = 25600; }
  else             { A = a2_f; Wt = hf_w2; bi = bf2; K = 1024; outOff = 51200; }
  const int n0 = (jx & 3) << 6;

  const int t = threadIdx.x;
  const int rowS = t >> 2, koff = (t & 3) << 4;   // 64 rows x 16 k each

  const int lane = t & 63, wav = t >> 6;
  const int r = lane & 15, kb = lane >> 4;
  int aoff[2], boff[2][4];
  #pragma unroll
  for (int kk = 0; kk < 2; ++kk) {
    int row = wav * 16 + r;
    aoff[kk] = row * 128 + ((((kk << 2) + kb) ^ (row & 7)) << 4);
    #pragma unroll
    for (int ni = 0; ni < 4; ++ni) {
      int cl = ni * 16 + r;
      boff[kk][ni] = cl * 128 + ((((kk << 2) + kb) ^ (cl & 7)) << 4);
    }
  }

  f32x4 acc[4];
  #pragma unroll
  for (int ni = 0; ni < 4; ++ni) acc[ni] = (f32x4){0.f, 0.f, 0.f, 0.f};

  const int wrow = n0 + rowS;
  const float4 z4 = make_float4(0.f, 0.f, 0.f, 0.f);
  for (int kt = 0; kt < K; kt += 64) {
    const float4* ap = (const float4*)&A[(size_t)(m0 + rowS) * K + kt + koff];
    float4 fa[4], fb[4];
    #pragma unroll
    for (int j = 0; j < 4; ++j) fa[j] = ap[j];
    if (wrow < 200) {
      const float4* bp = (const float4*)&Wt[(size_t)wrow * K + kt + koff];
      #pragma unroll
      for (int j = 0; j < 4; ++j) fb[j] = bp[j];
    } else {
      #pragma unroll
      for (int j = 0; j < 4; ++j) fb[j] = z4;
    }
    __syncthreads();
    #pragma unroll
    for (int j = 0; j < 2; ++j) {
      bf16x8 va, vb;
      va[0] = (short)f2bf(fa[2*j].x);   va[1] = (short)f2bf(fa[2*j].y);
      va[2] = (short)f2bf(fa[2*j].z);   va[3] = (short)f2bf(fa[2*j].w);
      va[4] = (short)f2bf(fa[2*j+1].x); va[5] = (short)f2bf(fa[2*j+1].y);
      va[6] = (short)f2bf(fa[2*j+1].z); va[7] = (short)f2bf(fa[2*j+1].w);
      vb[0] = (short)f2bf(fb[2*j].x);   vb[1] = (short)f2bf(fb[2*j].y);
      vb[2] = (short)f2bf(fb[2*j].z);   vb[3] = (short)f2bf(fb[2*j].w);
      vb[4] = (short)f2bf(fb[2*j+1].x); vb[5] = (short)f2bf(fb[2*j+1].y);
      vb[6] = (short)f2bf(fb[2*j+1].z); vb[7] = (short)f2bf(fb[2*j+1].w);
      int slot = (koff >> 3) + j;
      *(bf16x8*)((char*)As + rowS * 128 + ((slot ^ (rowS & 7)) << 4)) = va;
      *(bf16x8*)((char*)Bs + rowS * 128 + ((slot ^ (rowS & 7)) << 4)) = vb;
    }
    __syncthreads();
    #pragma unroll
    for (int kk = 0; kk < 2; ++kk) {
      bf16x8 a0 = *(bf16x8*)((char*)As + aoff[kk]);
      bf16x8 b0 = *(bf16x8*)((char*)Bs + boff[kk][0]);
      bf16x8 b1 = *(bf16x8*)((char*)Bs + boff[kk][1]);
      bf16x8 b2 = *(bf16x8*)((char*)Bs + boff[kk][2]);
      bf16x8 b3 = *(bf16x8*)((char*)Bs + boff[kk][3]);
      acc[0] = __builtin_amdgcn_mfma_f32_16x16x32_bf16(a0, b0, acc[0], 0, 0, 0);
      acc[1] = __builtin_amdgcn_mfma_f32_16x16x32_bf16(a0, b1, acc[1], 0, 0, 0);
      acc[2] = __builtin_amdgcn_mfma_f32_16x16x32_bf16(a0, b2, acc[2], 0, 0, 0);
      acc[3] = __builtin_amdgcn_mfma_f32_16x16x32_bf16(a0, b3, acc[3], 0, 0, 0);
    }
  }

  float* O = out + outOff;
  #pragma unroll
  for (int ni = 0; ni < 4; ++ni) {
    int cl = n0 + ni * 16 + r;
    if (cl < 200) {
      float bv = bi[cl];
      int row = m0 + wav * 16 + kb * 4;
      #pragma unroll
      for (int g2 = 0; g2 < 4; ++g2)
        O[(size_t)(row + g2) * 200 + cl] = acc[ni][g2] + bv;
    }
  }
}

// ---------------------------------------------------------------------------
extern "C" void kernel_launch(void* const* d_in, const int* in_sizes, int n_in,
                              void* d_out, int out_size, void* d_ws, size_t ws_size,
                              hipStream_t stream) {
  const float* x      = (const float*)d_in[0];
  const float* g_bn_g = (const float*)d_in[1];
  const float* g_bn_b = (const float*)d_in[2];
  const float* g_w    = (const float*)d_in[3];
  const float* g_b    = (const float*)d_in[4];
  const float* e_w    = (const float*)d_in[5];
  const float* e_b    = (const float*)d_in[6];
  const float* e_g    = (const float*)d_in[7];
  const float* e_bb   = (const float*)d_in[8];
  const float* hl_g1  = (const float*)d_in[9];
  const float* hl_b1  = (const float*)d_in[10];
  const float* hl_w1  = (const float*)d_in[11];
  const float* hl_bi1 = (const float*)d_in[12];
  const float* hl_g2  = (const float*)d_in[13];
  const float* hl_b2  = (const float*)d_in[14];
  const float* hl_w2  = (const float*)d_in[15];
  const float* hl_bi2 = (const float*)d_in[16];
  const float* hh_g1  = (const float*)d_in[17];
  const float* hh_b1  = (const float*)d_in[18];
  const float* hh_w1  = (const float*)d_in[19];
  const float* hh_bi1 = (const float*)d_in[20];
  const float* hh_g2  = (const float*)d_in[21];
  const float* hh_b2  = (const float*)d_in[22];
  const float* hh_w2  = (const float*)d_in[23];
  const float* hh_bi2 = (const float*)d_in[24];
  const float* hf_g1  = (const float*)d_in[25];
  const float* hf_b1  = (const float*)d_in[26];
  const float* hf_w1  = (const float*)d_in[27];
  const float* hf_bi1 = (const float*)d_in[28];
  const float* hf_g2  = (const float*)d_in[29];
  const float* hf_b2  = (const float*)d_in[30];
  const float* hf_w2  = (const float*)d_in[31];
  const float* hf_bi2 = (const float*)d_in[32];
  float* out = (float*)d_out;

  float* W = (float*)d_ws;
  const size_t BC = (size_t)B_DIM * C_DIM;   // 262144
  float* mp   = W;
  float* ms   = mp + BC;
  float* pool = ms + BC * 4;
  float* xl   = pool + BC;
  float* a2_l = xl + BC;
  float* a2_h = a2_l + 128 * 512;
  float* a2_f = a2_h + 128 * 512;
  float* st   = a2_f + 128 * 1024;
  float* mean_mp = st;           float* rstd_mp = st + 2048;
  float* s_h  = st + 2 * 2048;   float* t_h  = st + 3 * 2048;
  float* sf2  = st + 4 * 2048;   float* tf2  = st + 5 * 2048;
  float* s_l  = st + 6 * 2048;   float* t_l  = st + 7 * 2048;
  float* sf1  = st + 8 * 2048;   float* tf1  = st + 9 * 2048;
  float* P_e  = st + 10 * 2048;                 // 8 x 262144
  float* P_l2 = P_e + 8 * BC;                   // 16 x 65536
  float* P_hh = P_l2 + (size_t)16 * 65536;      // 16 x 65536
  float* P_f  = P_hh + (size_t)16 * 65536;      // 16 x 131072

  pool_max_kernel<<<16384, 256, 0, stream>>>(x, mp, ms);

  statsmp_kernel<<<128, 256, 0, stream>>>(mp, hh_g1, hh_b1, hf_g1, hf_b1,
                                          mean_mp, rstd_mp, s_h, t_h, sf2, tf2);

  gate_select_kernel<<<128, 256, 0, stream>>>(mp, mean_mp, rstd_mp, g_bn_g, g_bn_b,
                                              g_w, g_b, ms, pool);

  gemm_e_mfma_kernel<<<dim3(32, 8), 256, 0, stream>>>(pool, e_w, P_e);

  expert_fused_kernel<<<128, 256, 0, stream>>>(P_e, e_b, e_g, e_bb,
                                               hl_g1, hl_b1, hf_g1, hf_b1,
                                               xl, s_l, t_l, sf1, tf1);

  gemm_w1_mfma_kernel<<<dim3(32, 16), 256, 0, stream>>>(
      xl, mp, s_l, t_l, s_h, t_h, sf1, tf1, sf2, tf2,
      hl_w1, hh_w1, hf_w1, P_l2, P_hh, P_f);

  heads_fused_kernel<<<128, 256, 0, stream>>>(
      P_l2, P_hh, P_f, hl_bi1, hh_bi1, hf_bi1,
      hl_g2, hl_b2, hh_g2, hh_b2, hf_g2, hf_b2,
      a2_l, a2_h, a2_f);

  gemm_w2_mfma_kernel<<<dim3(12, 2), 256, 0, stream>>>(
      a2_l, a2_h, a2_f, hl_w2, hh_w2, hf_w2,
      hl_bi2, hh_bi2, hf_bi2, out);
}

// Round 10
// 131.697 us; speedup vs baseline: 1.1936x; 1.1197x over previous
//
#include <hip/hip_runtime.h>
#include <math.h>

#define B_DIM 128
#define C_DIM 2048
#define HW2   196

typedef __attribute__((ext_vector_type(8))) short bf16x8;
typedef __attribute__((ext_vector_type(4))) float f32x4;

__device__ __forceinline__ unsigned short f2bf(float f) {
  unsigned u = __float_as_uint(f);
  u += 0x7FFFu + ((u >> 16) & 1u);     // RNE
  return (unsigned short)(u >> 16);
}

// ---------------------------------------------------------------------------
// K1: per-(b,c) 14x14 tile -> global max (mp) + 4-scale adaptive avg-pool max.
// ---------------------------------------------------------------------------
__global__ __launch_bounds__(256) void pool_max_kernel(
    const float* __restrict__ x, float* __restrict__ mp, float* __restrict__ ms) {
  __shared__ float lds[4][4][208];
  const int tid  = threadIdx.x;
  const int w    = tid >> 6;
  const int lane = tid & 63;
  const int g    = lane >> 4;
  const int c    = lane & 15;
  const size_t waveBase = (size_t)blockIdx.x * 16 + w * 4;

  const float* src = x + waveBase * HW2;
  #pragma unroll
  for (int j = 0; j < 4; ++j) {
    int f = lane + 64 * j;
    if (f < 196) {
      int t = (f * 669) >> 15;       // f / 49
      float4 v = *(const float4*)(src + f * 4);
      *(float4*)&lds[w][t][(f - 49 * t) * 4] = v;
    }
  }

  float xv[14];
  const float* col = &lds[w][g][c];
  #pragma unroll
  for (int r = 0; r < 14; ++r) xv[r] = col[r * 14];

  float cmax = (c < 14) ? xv[0] : -INFINITY;
  #pragma unroll
  for (int r = 1; r < 14; ++r) if (c < 14) cmax = fmaxf(cmax, xv[r]);
  #pragma unroll
  for (int off = 8; off > 0; off >>= 1) cmax = fmaxf(cmax, __shfl_xor(cmax, off));

  float P[15];
  P[0] = 0.f;
  #pragma unroll
  for (int r = 0; r < 14; ++r) P[r + 1] = P[r] + xv[r];

  float sm0, sm1, sm2, sm3;

  { // k=4
    constexpr int rs[4] = {0, 3, 7, 10}, re[4] = {4, 7, 11, 14};
    const bool valid = (0x489u >> c) & 1;
    float vmax = -INFINITY;
    #pragma unroll
    for (int i = 0; i < 4; ++i) {
      float v  = P[re[i]] - P[rs[i]];
      float w2 = v + __shfl_down(v, 1);
      float w4 = w2 + __shfl_down(w2, 2);
      vmax = fmaxf(vmax, valid ? w4 : -INFINITY);
    }
    #pragma unroll
    for (int off = 8; off > 0; off >>= 1) vmax = fmaxf(vmax, __shfl_xor(vmax, off));
    sm0 = vmax * 0.0625f;
  }
  { // k=5
    constexpr int rs[5] = {0, 2, 5, 8, 11}, re[5] = {3, 6, 9, 12, 14};
    constexpr float srl[5] = {1.f/3.f, 0.25f, 0.25f, 0.25f, 1.f/3.f};
    const bool valid = (0x925u >> c) & 1;
    const bool is3   = (0x801u >> c) & 1;
    const float invc = is3 ? (1.f/3.f) : 0.25f;
    float vmax = -INFINITY;
    #pragma unroll
    for (int i = 0; i < 5; ++i) {
      float v  = P[re[i]] - P[rs[i]];
      float d1 = __shfl_down(v, 1);
      float d2 = __shfl_down(v, 2);
      float w2 = v + d1;
      float w3 = w2 + d2;
      float w4 = w2 + __shfl_down(w2, 2);
      float wv = (is3 ? w3 : w4) * invc * srl[i];
      vmax = fmaxf(vmax, valid ? wv : -INFINITY);
    }
    #pragma unroll
    for (int off = 8; off > 0; off >>= 1) vmax = fmaxf(vmax, __shfl_xor(vmax, off));
    sm1 = vmax;
  }
  { // k=7
    constexpr int rs[7] = {0, 2, 4, 6, 8, 10, 12};
    const bool valid = (0x1555u >> c) & 1;
    float vmax = -INFINITY;
    #pragma unroll
    for (int i = 0; i < 7; ++i) {
      float v  = P[rs[i] + 2] - P[rs[i]];
      float w2 = v + __shfl_down(v, 1);
      vmax = fmaxf(vmax, valid ? w2 : -INFINITY);
    }
    #pragma unroll
    for (int off = 8; off > 0; off >>= 1) vmax = fmaxf(vmax, __shfl_xor(vmax, off));
    sm2 = vmax * 0.25f;
  }
  { // k=11
    constexpr int rs[11] = {0, 1, 2, 3, 5, 6, 7, 8, 10, 11, 12};
    constexpr int re[11] = {2, 3, 4, 6, 7, 8, 9, 11, 12, 13, 14};
    constexpr float srl[11] = {0.5f, 0.5f, 0.5f, 1.f/3.f, 0.5f, 0.5f, 0.5f,
                               1.f/3.f, 0.5f, 0.5f, 0.5f};
    const bool valid = (0x1DEFu >> c) & 1;
    const bool is3   = (0x108u >> c) & 1;
    const float invc = is3 ? (1.f/3.f) : 0.5f;
    float vmax = -INFINITY;
    #pragma unroll
    for (int i = 0; i < 11; ++i) {
      float v  = P[re[i]] - P[rs[i]];
      float d1 = __shfl_down(v, 1);
      float d2 = __shfl_down(v, 2);
      float w2 = v + d1;
      float w3 = w2 + d2;
      float wv = (is3 ? w3 : w2) * invc * srl[i];
      vmax = fmaxf(vmax, valid ? wv : -INFINITY);
    }
    #pragma unroll
    for (int off = 8; off > 0; off >>= 1) vmax = fmaxf(vmax, __shfl_xor(vmax, off));
    sm3 = vmax;
  }

  if (c == 0) {
    size_t T = waveBase + g;
    mp[T] = cmax;
    *(float4*)&ms[T * 4] = make_float4(sm0, sm1, sm2, sm3);
  }
}

// ---------------------------------------------------------------------------
// K2: mp column stats + affine params (hh head, hf second half)
// ---------------------------------------------------------------------------
__global__ __launch_bounds__(256) void statsmp_kernel(
    const float* __restrict__ mp,
    const float* __restrict__ hh_g1, const float* __restrict__ hh_b1,
    const float* __restrict__ hf_g1, const float* __restrict__ hf_b1,
    float* __restrict__ mean_mp, float* __restrict__ rstd_mp,
    float* __restrict__ s_h, float* __restrict__ t_h,
    float* __restrict__ sf2, float* __restrict__ tf2) {
  const int ci = threadIdx.x & 15;
  const int g  = threadIdx.x >> 4;
  const int c  = blockIdx.x * 16 + ci;
  float s = 0.f, q = 0.f;
  #pragma unroll
  for (int r = 0; r < 8; ++r) {
    float v = mp[(size_t)(g * 8 + r) * C_DIM + c];
    s += v; q += v * v;
  }
  __shared__ float ss[16][16], qq[16][16];
  ss[g][ci] = s; qq[g][ci] = q;
  __syncthreads();
  if (g == 0) {
    float S = 0.f, Q = 0.f;
    #pragma unroll
    for (int j = 0; j < 16; ++j) { S += ss[j][ci]; Q += qq[j][ci]; }
    float m = S * (1.f / B_DIM);
    float var = Q * (1.f / B_DIM) - m * m;
    if (var < 0.f) var = 0.f;
    float r = rsqrtf(var + 1e-5f);
    mean_mp[c] = m; rstd_mp[c] = r;
    float a = r * hh_g1[c];        s_h[c] = a; t_h[c] = hh_b1[c] - m * a;
    float b = r * hf_g1[2048 + c]; sf2[c] = b; tf2[c] = hf_b1[2048 + c] - m * b;
  }
}

// ---------------------------------------------------------------------------
// K3: gate (BN+ELU+linear+argmax) fused with gated scale select -> pool
// ---------------------------------------------------------------------------
__global__ void gate_select_kernel(
    const float* __restrict__ mp,
    const float* __restrict__ mean, const float* __restrict__ rstd,
    const float* __restrict__ gg, const float* __restrict__ gb,
    const float* __restrict__ gw, const float* __restrict__ gbias,
    const float* __restrict__ ms, float* __restrict__ pool) {
  const int b = blockIdx.x;
  const int t = threadIdx.x;
  float s0 = 0.f, s1 = 0.f, s2 = 0.f, s3 = 0.f;
  for (int c = t; c < C_DIM; c += 256) {
    float v = mp[(size_t)b * C_DIM + c];
    float xn = (v - mean[c]) * rstd[c] * gg[c] + gb[c];
    float e = xn > 0.f ? xn : expm1f(xn);
    s0 += e * gw[c];
    s1 += e * gw[C_DIM + c];
    s2 += e * gw[2 * C_DIM + c];
    s3 += e * gw[3 * C_DIM + c];
  }
  __shared__ float red[4][256];
  __shared__ int ssel;
  red[0][t] = s0; red[1][t] = s1; red[2][t] = s2; red[3][t] = s3;
  __syncthreads();
  for (int st = 128; st > 0; st >>= 1) {
    if (t < st) {
      red[0][t] += red[0][t + st];
      red[1][t] += red[1][t + st];
      red[2][t] += red[2][t + st];
      red[3][t] += red[3][t + st];
    }
    __syncthreads();
  }
  if (t == 0) {
    float best = red[0][0] + gbias[0];
    int bi = 0;
    for (int j = 1; j < 4; ++j) {
      float l = red[j][0] + gbias[j];
      if (l > best) { best = l; bi = j; }
    }
    ssel = bi;
  }
  __syncthreads();
  const int sel = ssel;
  for (int c = t; c < C_DIM; c += 256)
    pool[(size_t)b * C_DIM + c] = ms[((size_t)b * C_DIM + c) * 4 + sel];
}

// ---------------------------------------------------------------------------
// K4: expert GEMM, bf16 MFMA. BM=128 BN=64 BK=64, grid (32, z=8), Kc=256.
// ---------------------------------------------------------------------------
__global__ __launch_bounds__(256) void gemm_e_mfma_kernel(
    const float* __restrict__ A, const float* __restrict__ W,
    float* __restrict__ P) {
  __shared__ __align__(16) short As[128 * 64];
  __shared__ __align__(16) short Bs[64 * 64];
  const int t = threadIdx.x;
  const int n0 = blockIdx.x << 6;
  const int kbeg = blockIdx.y << 8;          // Kc = 256

  const int rowA = t >> 1, koffA = (t & 1) << 5;
  const int rowB = t >> 2, koffB = (t & 3) << 4;

  const int lane = t & 63, wav = t >> 6;
  const int r = lane & 15, kb = lane >> 4;
  int aoff[2][2], boff[2][4];
  #pragma unroll
  for (int kk = 0; kk < 2; ++kk) {
    #pragma unroll
    for (int mi = 0; mi < 2; ++mi) {
      int row = wav * 32 + mi * 16 + r;
      aoff[kk][mi] = row * 128 + ((((kk << 2) + kb) ^ (row & 7)) << 4);
    }
    #pragma unroll
    for (int ni = 0; ni < 4; ++ni) {
      int cl = ni * 16 + r;
      boff[kk][ni] = cl * 128 + ((((kk << 2) + kb) ^ (cl & 7)) << 4);
    }
  }

  f32x4 acc[2][4];
  #pragma unroll
  for (int mi = 0; mi < 2; ++mi)
    #pragma unroll
    for (int ni = 0; ni < 4; ++ni)
      acc[mi][ni] = (f32x4){0.f, 0.f, 0.f, 0.f};

  for (int kt = 0; kt < 256; kt += 64) {
    const int kg = kbeg + kt;
    const float4* ap = (const float4*)&A[(size_t)rowA * 2048 + kg + koffA];
    const float4* bp = (const float4*)&W[(size_t)(n0 + rowB) * 2048 + kg + koffB];
    float4 fa[8], fb[4];
    #pragma unroll
    for (int j = 0; j < 8; ++j) fa[j] = ap[j];
    #pragma unroll
    for (int j = 0; j < 4; ++j) fb[j] = bp[j];
    __syncthreads();
    #pragma unroll
    for (int j = 0; j < 4; ++j) {
      bf16x8 v;
      v[0] = (short)f2bf(fa[2*j].x);   v[1] = (short)f2bf(fa[2*j].y);
      v[2] = (short)f2bf(fa[2*j].z);   v[3] = (short)f2bf(fa[2*j].w);
      v[4] = (short)f2bf(fa[2*j+1].x); v[5] = (short)f2bf(fa[2*j+1].y);
      v[6] = (short)f2bf(fa[2*j+1].z); v[7] = (short)f2bf(fa[2*j+1].w);
      int slot = (koffA >> 3) + j;
      *(bf16x8*)((char*)As + rowA * 128 + ((slot ^ (rowA & 7)) << 4)) = v;
    }
    #pragma unroll
    for (int j = 0; j < 2; ++j) {
      bf16x8 v;
      v[0] = (short)f2bf(fb[2*j].x);   v[1] = (short)f2bf(fb[2*j].y);
      v[2] = (short)f2bf(fb[2*j].z);   v[3] = (short)f2bf(fb[2*j].w);
      v[4] = (short)f2bf(fb[2*j+1].x); v[5] = (short)f2bf(fb[2*j+1].y);
      v[6] = (short)f2bf(fb[2*j+1].z); v[7] = (short)f2bf(fb[2*j+1].w);
      int slot = (koffB >> 3) + j;
      *(bf16x8*)((char*)Bs + rowB * 128 + ((slot ^ (rowB & 7)) << 4)) = v;
    }
    __syncthreads();
    #pragma unroll
    for (int kk = 0; kk < 2; ++kk) {
      bf16x8 a0 = *(bf16x8*)((char*)As + aoff[kk][0]);
      bf16x8 a1 = *(bf16x8*)((char*)As + aoff[kk][1]);
      bf16x8 b0 = *(bf16x8*)((char*)Bs + boff[kk][0]);
      bf16x8 b1 = *(bf16x8*)((char*)Bs + boff[kk][1]);
      bf16x8 b2 = *(bf16x8*)((char*)Bs + boff[kk][2]);
      bf16x8 b3 = *(bf16x8*)((char*)Bs + boff[kk][3]);
      acc[0][0] = __builtin_amdgcn_mfma_f32_16x16x32_bf16(a0, b0, acc[0][0], 0, 0, 0);
      acc[0][1] = __builtin_amdgcn_mfma_f32_16x16x32_bf16(a0, b1, acc[0][1], 0, 0, 0);
      acc[0][2] = __builtin_amdgcn_mfma_f32_16x16x32_bf16(a0, b2, acc[0][2], 0, 0, 0);
      acc[0][3] = __builtin_amdgcn_mfma_f32_16x16x32_bf16(a0, b3, acc[0][3], 0, 0, 0);
      acc[1][0] = __builtin_amdgcn_mfma_f32_16x16x32_bf16(a1, b0, acc[1][0], 0, 0, 0);
      acc[1][1] = __builtin_amdgcn_mfma_f32_16x16x32_bf16(a1, b1, acc[1][1], 0, 0, 0);
      acc[1][2] = __builtin_amdgcn_mfma_f32_16x16x32_bf16(a1, b2, acc[1][2], 0, 0, 0);
      acc[1][3] = __builtin_amdgcn_mfma_f32_16x16x32_bf16(a1, b3, acc[1][3], 0, 0, 0);
    }
  }

  float* Pz = P + ((size_t)blockIdx.y << 18);
  #pragma unroll
  for (int mi = 0; mi < 2; ++mi) {
    int row = wav * 32 + mi * 16 + kb * 4;
    #pragma unroll
    for (int ni = 0; ni < 4; ++ni) {
      int cl = n0 + ni * 16 + r;
      #pragma unroll
      for (int g2 = 0; g2 < 4; ++g2)
        Pz[(size_t)(row + g2) * 2048 + cl] = acc[mi][ni][g2];
    }
  }
}

// ---------------------------------------------------------------------------
// K5: expert fused epilogue (reduce 8 partials + bias -> BN -> relu -> stats)
// ---------------------------------------------------------------------------
__global__ __launch_bounds__(256) void expert_fused_kernel(
    const float* __restrict__ Pe, const float* __restrict__ e_b,
    const float* __restrict__ e_g, const float* __restrict__ e_bb,
    const float* __restrict__ hl_g1, const float* __restrict__ hl_b1,
    const float* __restrict__ hf_g1, const float* __restrict__ hf_b1,
    float* __restrict__ xl,
    float* __restrict__ s_l, float* __restrict__ t_l,
    float* __restrict__ sf1, float* __restrict__ tf1) {
  const int ci = threadIdx.x & 15;
  const int g  = threadIdx.x >> 4;
  const int c  = blockIdx.x * 16 + ci;
  float v[8];
  float s = 0.f, q = 0.f;
  const float bias = e_b[c];
  #pragma unroll
  for (int r = 0; r < 8; ++r) {
    const size_t row = g * 8 + r;
    float acc = bias;
    #pragma unroll
    for (int z = 0; z < 8; ++z)
      acc += Pe[((size_t)z << 18) + row * 2048 + c];
    v[r] = acc; s += acc; q += acc * acc;
  }
  __shared__ float ss[16][16], qq[16][16];
  __shared__ float sm[16], sr[16];
  ss[g][ci] = s; qq[g][ci] = q;
  __syncthreads();
  if (g == 0) {
    float S = 0.f, Q = 0.f;
    #pragma unroll
    for (int j = 0; j < 16; ++j) { S += ss[j][ci]; Q += qq[j][ci]; }
    float m = S * (1.f / B_DIM);
    float var = Q * (1.f / B_DIM) - m * m;
    if (var < 0.f) var = 0.f;
    sm[ci] = m; sr[ci] = rsqrtf(var + 1e-5f);
  }
  __syncthreads();
  const float m = sm[ci], rst = sr[ci];
  const float eg = e_g[c], eb2 = e_bb[c];
  float s2 = 0.f, q2 = 0.f;
  #pragma unroll
  for (int r = 0; r < 8; ++r) {
    float xv = fmaxf((v[r] - m) * rst * eg + eb2, 0.f);
    xl[(size_t)(g * 8 + r) * 2048 + c] = xv;
    s2 += xv; q2 += xv * xv;
  }
  __syncthreads();
  ss[g][ci] = s2; qq[g][ci] = q2;
  __syncthreads();
  if (g == 0) {
    float S = 0.f, Q = 0.f;
    #pragma unroll
    for (int j = 0; j < 16; ++j) { S += ss[j][ci]; Q += qq[j][ci]; }
    float mm = S * (1.f / B_DIM);
    float var = Q * (1.f / B_DIM) - mm * mm;
    if (var < 0.f) var = 0.f;
    float rr = rsqrtf(var + 1e-5f);
    float a = rr * hl_g1[c]; s_l[c] = a; t_l[c] = hl_b1[c] - mm * a;
    float b = rr * hf_g1[c]; sf1[c] = b; tf1[c] = hf_b1[c] - mm * b;
  }
}

// ---------------------------------------------------------------------------
// K6: combined head-linear1 GEMM, bf16 MFMA, BN1 affine folded into A staging.
// BM=64 / z=8 (vs R7's BM=128/z=16): same 512 blocks (2/CU), same A+W traffic,
// HALF the split-K partial traffic. grid (32, 2, 8): bx=job, by=m-half, bz=z.
// jobs: [0,8)=hl, [8,16)=hh, [16,32)=hf. Kc: l/h=256, f=512.
// ---------------------------------------------------------------------------
__global__ __launch_bounds__(256) void gemm_w1_mfma_kernel(
    const float* __restrict__ xl, const float* __restrict__ mp,
    const float* __restrict__ s_l, const float* __restrict__ t_l,
    const float* __restrict__ s_h, const float* __restrict__ t_h,
    const float* __restrict__ sf1, const float* __restrict__ tf1,
    const float* __restrict__ sf2, const float* __restrict__ tf2,
    const float* __restrict__ hl_w1, const float* __restrict__ hh_w1,
    const float* __restrict__ hf_w1,
    float* __restrict__ P_l, float* __restrict__ P_h, float* __restrict__ P_f) {
  __shared__ __align__(16) short As[64 * 64];
  __shared__ __align__(16) short Bs[64 * 64];
  const int jx = blockIdx.x;
  const int m0 = blockIdx.y << 6;
  const int z  = blockIdx.z;
  const float *A, *S, *T, *Wt;
  float* P;
  int N, Kdim, n0, kA0, kW0, Kc;
  if (jx < 8) {
    N = 512; Kdim = 2048; Kc = 256; Wt = hl_w1; n0 = jx << 6;
    kW0 = z * 256; kA0 = kW0; A = xl; S = s_l; T = t_l;
    P = P_l + ((size_t)z << 16);
  } else if (jx < 16) {
    N = 512; Kdim = 2048; Kc = 256; Wt = hh_w1; n0 = (jx - 8) << 6;
    kW0 = z * 256; kA0 = kW0; A = mp; S = s_h; T = t_h;
    P = P_h + ((size_t)z << 16);
  } else {
    N = 1024; Kdim = 4096; Kc = 512; Wt = hf_w1; n0 = (jx - 16) << 6;
    kW0 = z * 512;
    if (kW0 >= 2048) { A = mp; S = sf2; T = tf2; kA0 = kW0 - 2048; }
    else             { A = xl; S = sf1; T = tf1; kA0 = kW0; }
    P = P_f + ((size_t)z << 17);
  }
  const int t = threadIdx.x;
  const int rowS = t >> 2, koff = (t & 3) << 4;   // 64 rows x 16 floats each

  const int lane = t & 63, wav = t >> 6;
  const int r = lane & 15, kb = lane >> 4;
  int aoff[2], boff[2][4];
  #pragma unroll
  for (int kk = 0; kk < 2; ++kk) {
    int row = wav * 16 + r;
    aoff[kk] = row * 128 + ((((kk << 2) + kb) ^ (row & 7)) << 4);
    #pragma unroll
    for (int ni = 0; ni < 4; ++ni) {
      int cl = ni * 16 + r;
      boff[kk][ni] = cl * 128 + ((((kk << 2) + kb) ^ (cl & 7)) << 4);
    }
  }

  f32x4 acc[4];
  #pragma unroll
  for (int ni = 0; ni < 4; ++ni) acc[ni] = (f32x4){0.f, 0.f, 0.f, 0.f};

  for (int kt = 0; kt < Kc; kt += 64) {
    const int ka = kA0 + kt + koff;
    const float4* ap = (const float4*)&A[(size_t)(m0 + rowS) * 2048 + ka];
    const float4* sp = (const float4*)&S[ka];
    const float4* tp = (const float4*)&T[ka];
    const float4* bp = (const float4*)&Wt[(size_t)(n0 + rowS) * Kdim + kW0 + kt + koff];
    float4 fa[4], fb[4];
    #pragma unroll
    for (int j = 0; j < 4; ++j) fa[j] = ap[j];
    #pragma unroll
    for (int j = 0; j < 4; ++j) {
      float4 s4 = sp[j], t4 = tp[j];
      fa[j].x = fmaf(fa[j].x, s4.x, t4.x);
      fa[j].y = fmaf(fa[j].y, s4.y, t4.y);
      fa[j].z = fmaf(fa[j].z, s4.z, t4.z);
      fa[j].w = fmaf(fa[j].w, s4.w, t4.w);
    }
    #pragma unroll
    for (int j = 0; j < 4; ++j) fb[j] = bp[j];
    __syncthreads();
    #pragma unroll
    for (int j = 0; j < 2; ++j) {
      bf16x8 va, vb;
      va[0] = (short)f2bf(fa[2*j].x);   va[1] = (short)f2bf(fa[2*j].y);
      va[2] = (short)f2bf(fa[2*j].z);   va[3] = (short)f2bf(fa[2*j].w);
      va[4] = (short)f2bf(fa[2*j+1].x); va[5] = (short)f2bf(fa[2*j+1].y);
      va[6] = (short)f2bf(fa[2*j+1].z); va[7] = (short)f2bf(fa[2*j+1].w);
      vb[0] = (short)f2bf(fb[2*j].x);   vb[1] = (short)f2bf(fb[2*j].y);
      vb[2] = (short)f2bf(fb[2*j].z);   vb[3] = (short)f2bf(fb[2*j].w);
      vb[4] = (short)f2bf(fb[2*j+1].x); vb[5] = (short)f2bf(fb[2*j+1].y);
      vb[6] = (short)f2bf(fb[2*j+1].z); vb[7] = (short)f2bf(fb[2*j+1].w);
      int slot = (koff >> 3) + j;
      *(bf16x8*)((char*)As + rowS * 128 + ((slot ^ (rowS & 7)) << 4)) = va;
      *(bf16x8*)((char*)Bs + rowS * 128 + ((slot ^ (rowS & 7)) << 4)) = vb;
    }
    __syncthreads();
    #pragma unroll
    for (int kk = 0; kk < 2; ++kk) {
      bf16x8 a0 = *(bf16x8*)((char*)As + aoff[kk]);
      bf16x8 b0 = *(bf16x8*)((char*)Bs + boff[kk][0]);
      bf16x8 b1 = *(bf16x8*)((char*)Bs + boff[kk][1]);
      bf16x8 b2 = *(bf16x8*)((char*)Bs + boff[kk][2]);
      bf16x8 b3 = *(bf16x8*)((char*)Bs + boff[kk][3]);
      acc[0] = __builtin_amdgcn_mfma_f32_16x16x32_bf16(a0, b0, acc[0], 0, 0, 0);
      acc[1] = __builtin_amdgcn_mfma_f32_16x16x32_bf16(a0, b1, acc[1], 0, 0, 0);
      acc[2] = __builtin_amdgcn_mfma_f32_16x16x32_bf16(a0, b2, acc[2], 0, 0, 0);
      acc[3] = __builtin_amdgcn_mfma_f32_16x16x32_bf16(a0, b3, acc[3], 0, 0, 0);
    }
  }

  #pragma unroll
  for (int ni = 0; ni < 4; ++ni) {
    int cl = n0 + ni * 16 + r;
    int row = m0 + wav * 16 + kb * 4;
    #pragma unroll
    for (int g2 = 0; g2 < 4; ++g2)
      P[(size_t)(row + g2) * N + cl] = acc[ni][g2];
  }
}

// ---------------------------------------------------------------------------
// K7: heads fused epilogue (reduce 8 partial slices + bias -> BN -> ELU)
// ---------------------------------------------------------------------------
__global__ __launch_bounds__(256) void heads_fused_kernel(
    const float* __restrict__ P_l, const float* __restrict__ P_h,
    const float* __restrict__ P_f,
    const float* __restrict__ bl1, const float* __restrict__ bh1,
    const float* __restrict__ bf1,
    const float* __restrict__ g2l, const float* __restrict__ b2l,
    const float* __restrict__ g2h, const float* __restrict__ b2h,
    const float* __restrict__ g2f, const float* __restrict__ b2f,
    float* __restrict__ a2_l, float* __restrict__ a2_h, float* __restrict__ a2_f) {
  const int ci = threadIdx.x & 15;
  const int g  = threadIdx.x >> 4;
  const int cj = blockIdx.x * 16 + ci;
  const float *P, *bi, *g2, *b2;
  float* out;
  int N, cc;
  if (cj < 512)       { P = P_l; bi = bl1; g2 = g2l; b2 = b2l; out = a2_l; N = 512;  cc = cj; }
  else if (cj < 1024) { P = P_h; bi = bh1; g2 = g2h; b2 = b2h; out = a2_h; N = 512;  cc = cj - 512; }
  else                { P = P_f; bi = bf1; g2 = g2f; b2 = b2f; out = a2_f; N = 1024; cc = cj - 1024; }
  const size_t sstride = (size_t)N * 128;
  float v[8];
  float s = 0.f, q = 0.f;
  const float bias = bi[cc];
  #pragma unroll
  for (int r = 0; r < 8; ++r) {
    const size_t row = g * 8 + r;
    float acc = bias;
    #pragma unroll
    for (int z = 0; z < 8; ++z)
      acc += P[(size_t)z * sstride + row * N + cc];
    v[r] = acc; s += acc; q += acc * acc;
  }
  __shared__ float ss[16][16], qq[16][16];
  __shared__ float sm[16], sr[16];
  ss[g][ci] = s; qq[g][ci] = q;
  __syncthreads();
  if (g == 0) {
    float S = 0.f, Q = 0.f;
    #pragma unroll
    for (int j = 0; j < 16; ++j) { S += ss[j][ci]; Q += qq[j][ci]; }
    float m = S * (1.f / B_DIM);
    float var = Q * (1.f / B_DIM) - m * m;
    if (var < 0.f) var = 0.f;
    sm[ci] = m; sr[ci] = rsqrtf(var + 1e-5f);
  }
  __syncthreads();
  const float m = sm[ci], rr = sr[ci];
  const float gg = g2[cc], bb = b2[cc];
  #pragma unroll
  for (int r = 0; r < 8; ++r) {
    float xn = (v[r] - m) * rr * gg + bb;
    out[(size_t)(g * 8 + r) * N + cc] = xn > 0.f ? xn : expm1f(xn);
  }
}

// ---------------------------------------------------------------------------
// K8: combined head-linear2 split-K GEMM (fp32; R7 config). grid (12, 2, 8).
// ---------------------------------------------------------------------------
__global__ __launch_bounds__(256) void gemm_w2_kernel(
    const float* __restrict__ a2_l, const float* __restrict__ a2_h,
    const float* __restrict__ a2_f,
    const float* __restrict__ hl_w2, const float* __restrict__ hh_w2,
    const float* __restrict__ hf_w2,
    float* __restrict__ Pw) {
  const int jx = blockIdx.x;
  const int z  = blockIdx.z;
  const float *A, *Wt;
  int K, Kc, pOff, n0;
  if (jx < 4)      { A = a2_l; Wt = hl_w2; K = 512;  Kc = 64;  pOff = 0;     n0 = jx << 6; }
  else if (jx < 8) { A = a2_h; Wt = hh_w2; K = 512;  Kc = 64;  pOff = 25600; n0 = (jx - 4) << 6; }
  else             { A = a2_f; Wt = hf_w2; K = 1024; Kc = 128; pOff = 51200; n0 = (jx - 8) << 6; }
  const int kbeg = z * Kc;
  const int m0 = blockIdx.y << 6;
  __shared__ float As[32][68];
  __shared__ float Bs[32][68];
  const int t = threadIdx.x;
  const int lr = t >> 3;
  const int lk4 = (t & 7) << 2;
  const int tx = t & 15, ty = t >> 4;
  float acc[4][4] = {{0.f}};
  const float4 z4 = make_float4(0.f, 0.f, 0.f, 0.f);
  for (int k0 = kbeg; k0 < kbeg + Kc; k0 += 32) {
    float4 a0 = *(const float4*)&A[(size_t)(m0 + lr) * K + k0 + lk4];
    float4 a1 = *(const float4*)&A[(size_t)(m0 + lr + 32) * K + k0 + lk4];
    int n1 = n0 + lr, n2 = n0 + lr + 32;
    float4 b0 = (n1 < 200) ? *(const float4*)&Wt[(size_t)n1 * K + k0 + lk4] : z4;
    float4 b1 = (n2 < 200) ? *(const float4*)&Wt[(size_t)n2 * K + k0 + lk4] : z4;
    __syncthreads();
    As[lk4 + 0][lr] = a0.x; As[lk4 + 1][lr] = a0.y; As[lk4 + 2][lr] = a0.z; As[lk4 + 3][lr] = a0.w;
    As[lk4 + 0][lr + 32] = a1.x; As[lk4 + 1][lr + 32] = a1.y; As[lk4 + 2][lr + 32] = a1.z; As[lk4 + 3][lr + 32] = a1.w;
    Bs[lk4 + 0][lr] = b0.x; Bs[lk4 + 1][lr] = b0.y; Bs[lk4 + 2][lr] = b0.z; Bs[lk4 + 3][lr] = b0.w;
    Bs[lk4 + 0][lr + 32] = b1.x; Bs[lk4 + 1][lr + 32] = b1.y; Bs[lk4 + 2][lr + 32] = b1.z; Bs[lk4 + 3][lr + 32] = b1.w;
    __syncthreads();
    #pragma unroll
    for (int kk = 0; kk < 32; ++kk) {
      float4 av = *(const float4*)&As[kk][ty << 2];
      float4 bv = *(const float4*)&Bs[kk][tx << 2];
      acc[0][0] = fmaf(av.x, bv.x, acc[0][0]); acc[0][1] = fmaf(av.x, bv.y, acc[0][1]);
      acc[0][2] = fmaf(av.x, bv.z, acc[0][2]); acc[0][3] = fmaf(av.x, bv.w, acc[0][3]);
      acc[1][0] = fmaf(av.y, bv.x, acc[1][0]); acc[1][1] = fmaf(av.y, bv.y, acc[1][1]);
      acc[1][2] = fmaf(av.y, bv.z, acc[1][2]); acc[1][3] = fmaf(av.y, bv.w, acc[1][3]);
      acc[2][0] = fmaf(av.z, bv.x, acc[2][0]); acc[2][1] = fmaf(av.z, bv.y, acc[2][1]);
      acc[2][2] = fmaf(av.z, bv.z, acc[2][2]); acc[2][3] = fmaf(av.z, bv.w, acc[2][3]);
      acc[3][0] = fmaf(av.w, bv.x, acc[3][0]); acc[3][1] = fmaf(av.w, bv.y, acc[3][1]);
      acc[3][2] = fmaf(av.w, bv.z, acc[3][2]); acc[3][3] = fmaf(av.w, bv.w, acc[3][3]);
    }
  }
  float* Pz = Pw + (size_t)z * 76800 + pOff;
  #pragma unroll
  for (int i = 0; i < 4; ++i) {
    int m = m0 + (ty << 2) + i;
    #pragma unroll
    for (int j = 0; j < 4; ++j) {
      int n = n0 + (tx << 2) + j;
      if (n < 200) Pz[(size_t)m * 200 + n] = acc[i][j];
    }
  }
}

// K9: final reduce into out
__global__ void reduce_out_kernel(const float* __restrict__ P,
                                  const float* __restrict__ bl,
                                  const float* __restrict__ bh,
                                  const float* __restrict__ bf,
                                  float* __restrict__ out) {
  int i = blockIdx.x * 256 + threadIdx.x;
  if (i >= 76800) return;
  int job = i / 25600;
  int n = (i - job * 25600) % 200;
  float s = (job == 0) ? bl[n] : (job == 1) ? bh[n] : bf[n];
  for (int z = 0; z < 8; ++z) s += P[(size_t)z * 76800 + i];
  out[i] = s;
}

// ---------------------------------------------------------------------------
extern "C" void kernel_launch(void* const* d_in, const int* in_sizes, int n_in,
                              void* d_out, int out_size, void* d_ws, size_t ws_size,
                              hipStream_t stream) {
  const float* x      = (const float*)d_in[0];
  const float* g_bn_g = (const float*)d_in[1];
  const float* g_bn_b = (const float*)d_in[2];
  const float* g_w    = (const float*)d_in[3];
  const float* g_b    = (const float*)d_in[4];
  const float* e_w    = (const float*)d_in[5];
  const float* e_b    = (const float*)d_in[6];
  const float* e_g    = (const float*)d_in[7];
  const float* e_bb   = (const float*)d_in[8];
  const float* hl_g1  = (const float*)d_in[9];
  const float* hl_b1  = (const float*)d_in[10];
  const float* hl_w1  = (const float*)d_in[11];
  const float* hl_bi1 = (const float*)d_in[12];
  const float* hl_g2  = (const float*)d_in[13];
  const float* hl_b2  = (const float*)d_in[14];
  const float* hl_w2  = (const float*)d_in[15];
  const float* hl_bi2 = (const float*)d_in[16];
  const float* hh_g1  = (const float*)d_in[17];
  const float* hh_b1  = (const float*)d_in[18];
  const float* hh_w1  = (const float*)d_in[19];
  const float* hh_bi1 = (const float*)d_in[20];
  const float* hh_g2  = (const float*)d_in[21];
  const float* hh_b2  = (const float*)d_in[22];
  const float* hh_w2  = (const float*)d_in[23];
  const float* hh_bi2 = (const float*)d_in[24];
  const float* hf_g1  = (const float*)d_in[25];
  const float* hf_b1  = (const float*)d_in[26];
  const float* hf_w1  = (const float*)d_in[27];
  const float* hf_bi1 = (const float*)d_in[28];
  const float* hf_g2  = (const float*)d_in[29];
  const float* hf_b2  = (const float*)d_in[30];
  const float* hf_w2  = (const float*)d_in[31];
  const float* hf_bi2 = (const float*)d_in[32];
  float* out = (float*)d_out;

  float* W = (float*)d_ws;
  const size_t BC = (size_t)B_DIM * C_DIM;   // 262144
  float* mp   = W;
  float* ms   = mp + BC;
  float* pool = ms + BC * 4;
  float* xl   = pool + BC;
  float* a2_l = xl + BC;
  float* a2_h = a2_l + 128 * 512;
  float* a2_f = a2_h + 128 * 512;
  float* st   = a2_f + 128 * 1024;
  float* mean_mp = st;           float* rstd_mp = st + 2048;
  float* s_h  = st + 2 * 2048;   float* t_h  = st + 3 * 2048;
  float* sf2  = st + 4 * 2048;   float* tf2  = st + 5 * 2048;
  float* s_l  = st + 6 * 2048;   float* t_l  = st + 7 * 2048;
  float* sf1  = st + 8 * 2048;   float* tf1  = st + 9 * 2048;
  float* P_e  = st + 10 * 2048;                 // 8 x 262144 (reused as P_w2)
  float* P_l2 = P_e + 8 * BC;                   // 8 x 65536
  float* P_hh = P_l2 + (size_t)8 * 65536;       // 8 x 65536
  float* P_f  = P_hh + (size_t)8 * 65536;       // 8 x 131072
  float* P_w2 = P_e;

  pool_max_kernel<<<16384, 256, 0, stream>>>(x, mp, ms);

  statsmp_kernel<<<128, 256, 0, stream>>>(mp, hh_g1, hh_b1, hf_g1, hf_b1,
                                          mean_mp, rstd_mp, s_h, t_h, sf2, tf2);

  gate_select_kernel<<<128, 256, 0, stream>>>(mp, mean_mp, rstd_mp, g_bn_g, g_bn_b,
                                              g_w, g_b, ms, pool);

  gemm_e_mfma_kernel<<<dim3(32, 8), 256, 0, stream>>>(pool, e_w, P_e);

  expert_fused_kernel<<<128, 256, 0, stream>>>(P_e, e_b, e_g, e_bb,
                                               hl_g1, hl_b1, hf_g1, hf_b1,
                                               xl, s_l, t_l, sf1, tf1);

  gemm_w1_mfma_kernel<<<dim3(32, 2, 8), 256, 0, stream>>>(
      xl, mp, s_l, t_l, s_h, t_h, sf1, tf1, sf2, tf2,
      hl_w1, hh_w1, hf_w1, P_l2, P_hh, P_f);

  heads_fused_kernel<<<128, 256, 0, stream>>>(
      P_l2, P_hh, P_f, hl_bi1, hh_bi1, hf_bi1,
      hl_g2, hl_b2, hh_g2, hh_b2, hf_g2, hf_b2,
      a2_l, a2_h, a2_f);

  gemm_w2_kernel<<<dim3(12, 2, 8), 256, 0, stream>>>(
      a2_l, a2_h, a2_f, hl_w2, hh_w2, hf_w2, P_w2);

  reduce_out_kernel<<<300, 256, 0, stream>>>(P_w2, hl_bi2, hh_bi2, hf_bi2, out);
}

// Round 11
// 130.748 us; speedup vs baseline: 1.2023x; 1.0073x over previous
//
#include <hip/hip_runtime.h>
#include <math.h>

#define B_DIM 128
#define C_DIM 2048
#define HW2   196

typedef __attribute__((ext_vector_type(8))) short bf16x8;
typedef __attribute__((ext_vector_type(4))) float f32x4;

__device__ __forceinline__ unsigned short f2bf(float f) {
  unsigned u = __float_as_uint(f);
  u += 0x7FFFu + ((u >> 16) & 1u);     // RNE
  return (unsigned short)(u >> 16);
}

// ---------------------------------------------------------------------------
// K1: per-(b,c) 14x14 tile -> global max (mp) + 4-scale adaptive avg-pool max.
// ---------------------------------------------------------------------------
__global__ __launch_bounds__(256) void pool_max_kernel(
    const float* __restrict__ x, float* __restrict__ mp, float* __restrict__ ms) {
  __shared__ float lds[4][4][208];
  const int tid  = threadIdx.x;
  const int w    = tid >> 6;
  const int lane = tid & 63;
  const int g    = lane >> 4;
  const int c    = lane & 15;
  const size_t waveBase = (size_t)blockIdx.x * 16 + w * 4;

  const float* src = x + waveBase * HW2;
  #pragma unroll
  for (int j = 0; j < 4; ++j) {
    int f = lane + 64 * j;
    if (f < 196) {
      int t = (f * 669) >> 15;       // f / 49
      float4 v = *(const float4*)(src + f * 4);
      *(float4*)&lds[w][t][(f - 49 * t) * 4] = v;
    }
  }

  float xv[14];
  const float* col = &lds[w][g][c];
  #pragma unroll
  for (int r = 0; r < 14; ++r) xv[r] = col[r * 14];

  float cmax = (c < 14) ? xv[0] : -INFINITY;
  #pragma unroll
  for (int r = 1; r < 14; ++r) if (c < 14) cmax = fmaxf(cmax, xv[r]);
  #pragma unroll
  for (int off = 8; off > 0; off >>= 1) cmax = fmaxf(cmax, __shfl_xor(cmax, off));

  float P[15];
  P[0] = 0.f;
  #pragma unroll
  for (int r = 0; r < 14; ++r) P[r + 1] = P[r] + xv[r];

  float sm0, sm1, sm2, sm3;

  { // k=4
    constexpr int rs[4] = {0, 3, 7, 10}, re[4] = {4, 7, 11, 14};
    const bool valid = (0x489u >> c) & 1;
    float vmax = -INFINITY;
    #pragma unroll
    for (int i = 0; i < 4; ++i) {
      float v  = P[re[i]] - P[rs[i]];
      float w2 = v + __shfl_down(v, 1);
      float w4 = w2 + __shfl_down(w2, 2);
      vmax = fmaxf(vmax, valid ? w4 : -INFINITY);
    }
    #pragma unroll
    for (int off = 8; off > 0; off >>= 1) vmax = fmaxf(vmax, __shfl_xor(vmax, off));
    sm0 = vmax * 0.0625f;
  }
  { // k=5
    constexpr int rs[5] = {0, 2, 5, 8, 11}, re[5] = {3, 6, 9, 12, 14};
    constexpr float srl[5] = {1.f/3.f, 0.25f, 0.25f, 0.25f, 1.f/3.f};
    const bool valid = (0x925u >> c) & 1;
    const bool is3   = (0x801u >> c) & 1;
    const float invc = is3 ? (1.f/3.f) : 0.25f;
    float vmax = -INFINITY;
    #pragma unroll
    for (int i = 0; i < 5; ++i) {
      float v  = P[re[i]] - P[rs[i]];
      float d1 = __shfl_down(v, 1);
      float d2 = __shfl_down(v, 2);
      float w2 = v + d1;
      float w3 = w2 + d2;
      float w4 = w2 + __shfl_down(w2, 2);
      float wv = (is3 ? w3 : w4) * invc * srl[i];
      vmax = fmaxf(vmax, valid ? wv : -INFINITY);
    }
    #pragma unroll
    for (int off = 8; off > 0; off >>= 1) vmax = fmaxf(vmax, __shfl_xor(vmax, off));
    sm1 = vmax;
  }
  { // k=7
    constexpr int rs[7] = {0, 2, 4, 6, 8, 10, 12};
    const bool valid = (0x1555u >> c) & 1;
    float vmax = -INFINITY;
    #pragma unroll
    for (int i = 0; i < 7; ++i) {
      float v  = P[rs[i] + 2] - P[rs[i]];
      float w2 = v + __shfl_down(v, 1);
      vmax = fmaxf(vmax, valid ? w2 : -INFINITY);
    }
    #pragma unroll
    for (int off = 8; off > 0; off >>= 1) vmax = fmaxf(vmax, __shfl_xor(vmax, off));
    sm2 = vmax * 0.25f;
  }
  { // k=11
    constexpr int rs[11] = {0, 1, 2, 3, 5, 6, 7, 8, 10, 11, 12};
    constexpr int re[11] = {2, 3, 4, 6, 7, 8, 9, 11, 12, 13, 14};
    constexpr float srl[11] = {0.5f, 0.5f, 0.5f, 1.f/3.f, 0.5f, 0.5f, 0.5f,
                               1.f/3.f, 0.5f, 0.5f, 0.5f};
    const bool valid = (0x1DEFu >> c) & 1;
    const bool is3   = (0x108u >> c) & 1;
    const float invc = is3 ? (1.f/3.f) : 0.5f;
    float vmax = -INFINITY;
    #pragma unroll
    for (int i = 0; i < 11; ++i) {
      float v  = P[re[i]] - P[rs[i]];
      float d1 = __shfl_down(v, 1);
      float d2 = __shfl_down(v, 2);
      float w2 = v + d1;
      float w3 = w2 + d2;
      float wv = (is3 ? w3 : w2) * invc * srl[i];
      vmax = fmaxf(vmax, valid ? wv : -INFINITY);
    }
    #pragma unroll
    for (int off = 8; off > 0; off >>= 1) vmax = fmaxf(vmax, __shfl_xor(vmax, off));
    sm3 = vmax;
  }

  if (c == 0) {
    size_t T = waveBase + g;
    mp[T] = cmax;
    *(float4*)&ms[T * 4] = make_float4(sm0, sm1, sm2, sm3);
  }
}

// ---------------------------------------------------------------------------
// K2: mp column stats + affine params (hh head, hf second half)
// ---------------------------------------------------------------------------
__global__ __launch_bounds__(256) void statsmp_kernel(
    const float* __restrict__ mp,
    const float* __restrict__ hh_g1, const float* __restrict__ hh_b1,
    const float* __restrict__ hf_g1, const float* __restrict__ hf_b1,
    float* __restrict__ mean_mp, float* __restrict__ rstd_mp,
    float* __restrict__ s_h, float* __restrict__ t_h,
    float* __restrict__ sf2, float* __restrict__ tf2) {
  const int ci = threadIdx.x & 15;
  const int g  = threadIdx.x >> 4;
  const int c  = blockIdx.x * 16 + ci;
  float s = 0.f, q = 0.f;
  #pragma unroll
  for (int r = 0; r < 8; ++r) {
    float v = mp[(size_t)(g * 8 + r) * C_DIM + c];
    s += v; q += v * v;
  }
  __shared__ float ss[16][16], qq[16][16];
  ss[g][ci] = s; qq[g][ci] = q;
  __syncthreads();
  if (g == 0) {
    float S = 0.f, Q = 0.f;
    #pragma unroll
    for (int j = 0; j < 16; ++j) { S += ss[j][ci]; Q += qq[j][ci]; }
    float m = S * (1.f / B_DIM);
    float var = Q * (1.f / B_DIM) - m * m;
    if (var < 0.f) var = 0.f;
    float r = rsqrtf(var + 1e-5f);
    mean_mp[c] = m; rstd_mp[c] = r;
    float a = r * hh_g1[c];        s_h[c] = a; t_h[c] = hh_b1[c] - m * a;
    float b = r * hf_g1[2048 + c]; sf2[c] = b; tf2[c] = hf_b1[2048 + c] - m * b;
  }
}

// ---------------------------------------------------------------------------
// K3: gate (BN+ELU+linear+argmax) fused with gated scale select -> pool
// ---------------------------------------------------------------------------
__global__ void gate_select_kernel(
    const float* __restrict__ mp,
    const float* __restrict__ mean, const float* __restrict__ rstd,
    const float* __restrict__ gg, const float* __restrict__ gb,
    const float* __restrict__ gw, const float* __restrict__ gbias,
    const float* __restrict__ ms, float* __restrict__ pool) {
  const int b = blockIdx.x;
  const int t = threadIdx.x;
  float s0 = 0.f, s1 = 0.f, s2 = 0.f, s3 = 0.f;
  for (int c = t; c < C_DIM; c += 256) {
    float v = mp[(size_t)b * C_DIM + c];
    float xn = (v - mean[c]) * rstd[c] * gg[c] + gb[c];
    float e = xn > 0.f ? xn : expm1f(xn);
    s0 += e * gw[c];
    s1 += e * gw[C_DIM + c];
    s2 += e * gw[2 * C_DIM + c];
    s3 += e * gw[3 * C_DIM + c];
  }
  __shared__ float red[4][256];
  __shared__ int ssel;
  red[0][t] = s0; red[1][t] = s1; red[2][t] = s2; red[3][t] = s3;
  __syncthreads();
  for (int st = 128; st > 0; st >>= 1) {
    if (t < st) {
      red[0][t] += red[0][t + st];
      red[1][t] += red[1][t + st];
      red[2][t] += red[2][t + st];
      red[3][t] += red[3][t + st];
    }
    __syncthreads();
  }
  if (t == 0) {
    float best = red[0][0] + gbias[0];
    int bi = 0;
    for (int j = 1; j < 4; ++j) {
      float l = red[j][0] + gbias[j];
      if (l > best) { best = l; bi = j; }
    }
    ssel = bi;
  }
  __syncthreads();
  const int sel = ssel;
  for (int c = t; c < C_DIM; c += 256)
    pool[(size_t)b * C_DIM + c] = ms[((size_t)b * C_DIM + c) * 4 + sel];
}

// ---------------------------------------------------------------------------
// K4: expert GEMM, bf16 MFMA. BM=64 BN=64 BK=64, grid (32, 2, 8), Kc=256.
// 512 blocks = 2/CU (R10-w1-proven occupancy knee).
// ---------------------------------------------------------------------------
__global__ __launch_bounds__(256) void gemm_e_mfma_kernel(
    const float* __restrict__ A, const float* __restrict__ W,
    float* __restrict__ P) {
  __shared__ __align__(16) short As[64 * 64];
  __shared__ __align__(16) short Bs[64 * 64];
  const int t = threadIdx.x;
  const int n0 = blockIdx.x << 6;
  const int m0 = blockIdx.y << 6;
  const int kbeg = blockIdx.z << 8;          // Kc = 256

  const int rowS = t >> 2, koff = (t & 3) << 4;   // 64 rows x 16 floats

  const int lane = t & 63, wav = t >> 6;
  const int r = lane & 15, kb = lane >> 4;
  int aoff[2], boff[2][4];
  #pragma unroll
  for (int kk = 0; kk < 2; ++kk) {
    int row = wav * 16 + r;
    aoff[kk] = row * 128 + ((((kk << 2) + kb) ^ (row & 7)) << 4);
    #pragma unroll
    for (int ni = 0; ni < 4; ++ni) {
      int cl = ni * 16 + r;
      boff[kk][ni] = cl * 128 + ((((kk << 2) + kb) ^ (cl & 7)) << 4);
    }
  }

  f32x4 acc[4];
  #pragma unroll
  for (int ni = 0; ni < 4; ++ni) acc[ni] = (f32x4){0.f, 0.f, 0.f, 0.f};

  for (int kt = 0; kt < 256; kt += 64) {
    const int kg = kbeg + kt + koff;
    const float4* ap = (const float4*)&A[(size_t)(m0 + rowS) * 2048 + kg];
    const float4* bp = (const float4*)&W[(size_t)(n0 + rowS) * 2048 + kg];
    float4 fa[4], fb[4];
    #pragma unroll
    for (int j = 0; j < 4; ++j) fa[j] = ap[j];
    #pragma unroll
    for (int j = 0; j < 4; ++j) fb[j] = bp[j];
    __syncthreads();
    #pragma unroll
    for (int j = 0; j < 2; ++j) {
      bf16x8 va, vb;
      va[0] = (short)f2bf(fa[2*j].x);   va[1] = (short)f2bf(fa[2*j].y);
      va[2] = (short)f2bf(fa[2*j].z);   va[3] = (short)f2bf(fa[2*j].w);
      va[4] = (short)f2bf(fa[2*j+1].x); va[5] = (short)f2bf(fa[2*j+1].y);
      va[6] = (short)f2bf(fa[2*j+1].z); va[7] = (short)f2bf(fa[2*j+1].w);
      vb[0] = (short)f2bf(fb[2*j].x);   vb[1] = (short)f2bf(fb[2*j].y);
      vb[2] = (short)f2bf(fb[2*j].z);   vb[3] = (short)f2bf(fb[2*j].w);
      vb[4] = (short)f2bf(fb[2*j+1].x); vb[5] = (short)f2bf(fb[2*j+1].y);
      vb[6] = (short)f2bf(fb[2*j+1].z); vb[7] = (short)f2bf(fb[2*j+1].w);
      int slot = (koff >> 3) + j;
      *(bf16x8*)((char*)As + rowS * 128 + ((slot ^ (rowS & 7)) << 4)) = va;
      *(bf16x8*)((char*)Bs + rowS * 128 + ((slot ^ (rowS & 7)) << 4)) = vb;
    }
    __syncthreads();
    #pragma unroll
    for (int kk = 0; kk < 2; ++kk) {
      bf16x8 a0 = *(bf16x8*)((char*)As + aoff[kk]);
      bf16x8 b0 = *(bf16x8*)((char*)Bs + boff[kk][0]);
      bf16x8 b1 = *(bf16x8*)((char*)Bs + boff[kk][1]);
      bf16x8 b2 = *(bf16x8*)((char*)Bs + boff[kk][2]);
      bf16x8 b3 = *(bf16x8*)((char*)Bs + boff[kk][3]);
      acc[0] = __builtin_amdgcn_mfma_f32_16x16x32_bf16(a0, b0, acc[0], 0, 0, 0);
      acc[1] = __builtin_amdgcn_mfma_f32_16x16x32_bf16(a0, b1, acc[1], 0, 0, 0);
      acc[2] = __builtin_amdgcn_mfma_f32_16x16x32_bf16(a0, b2, acc[2], 0, 0, 0);
      acc[3] = __builtin_amdgcn_mfma_f32_16x16x32_bf16(a0, b3, acc[3], 0, 0, 0);
    }
  }

  float* Pz = P + ((size_t)blockIdx.z << 18);
  #pragma unroll
  for (int ni = 0; ni < 4; ++ni) {
    int cl = n0 + ni * 16 + r;
    int row = m0 + wav * 16 + kb * 4;
    #pragma unroll
    for (int g2 = 0; g2 < 4; ++g2)
      Pz[(size_t)(row + g2) * 2048 + cl] = acc[ni][g2];
  }
}

// ---------------------------------------------------------------------------
// K5: expert fused epilogue (reduce 8 partials + bias -> BN -> relu -> stats)
// ---------------------------------------------------------------------------
__global__ __launch_bounds__(256) void expert_fused_kernel(
    const float* __restrict__ Pe, const float* __restrict__ e_b,
    const float* __restrict__ e_g, const float* __restrict__ e_bb,
    const float* __restrict__ hl_g1, const float* __restrict__ hl_b1,
    const float* __restrict__ hf_g1, const float* __restrict__ hf_b1,
    float* __restrict__ xl,
    float* __restrict__ s_l, float* __restrict__ t_l,
    float* __restrict__ sf1, float* __restrict__ tf1) {
  const int ci = threadIdx.x & 15;
  const int g  = threadIdx.x >> 4;
  const int c  = blockIdx.x * 16 + ci;
  float v[8];
  float s = 0.f, q = 0.f;
  const float bias = e_b[c];
  #pragma unroll
  for (int r = 0; r < 8; ++r) {
    const size_t row = g * 8 + r;
    float acc = bias;
    #pragma unroll
    for (int z = 0; z < 8; ++z)
      acc += Pe[((size_t)z << 18) + row * 2048 + c];
    v[r] = acc; s += acc; q += acc * acc;
  }
  __shared__ float ss[16][16], qq[16][16];
  __shared__ float sm[16], sr[16];
  ss[g][ci] = s; qq[g][ci] = q;
  __syncthreads();
  if (g == 0) {
    float S = 0.f, Q = 0.f;
    #pragma unroll
    for (int j = 0; j < 16; ++j) { S += ss[j][ci]; Q += qq[j][ci]; }
    float m = S * (1.f / B_DIM);
    float var = Q * (1.f / B_DIM) - m * m;
    if (var < 0.f) var = 0.f;
    sm[ci] = m; sr[ci] = rsqrtf(var + 1e-5f);
  }
  __syncthreads();
  const float m = sm[ci], rst = sr[ci];
  const float eg = e_g[c], eb2 = e_bb[c];
  float s2 = 0.f, q2 = 0.f;
  #pragma unroll
  for (int r = 0; r < 8; ++r) {
    float xv = fmaxf((v[r] - m) * rst * eg + eb2, 0.f);
    xl[(size_t)(g * 8 + r) * 2048 + c] = xv;
    s2 += xv; q2 += xv * xv;
  }
  __syncthreads();
  ss[g][ci] = s2; qq[g][ci] = q2;
  __syncthreads();
  if (g == 0) {
    float S = 0.f, Q = 0.f;
    #pragma unroll
    for (int j = 0; j < 16; ++j) { S += ss[j][ci]; Q += qq[j][ci]; }
    float mm = S * (1.f / B_DIM);
    float var = Q * (1.f / B_DIM) - mm * mm;
    if (var < 0.f) var = 0.f;
    float rr = rsqrtf(var + 1e-5f);
    float a = rr * hl_g1[c]; s_l[c] = a; t_l[c] = hl_b1[c] - mm * a;
    float b = rr * hf_g1[c]; sf1[c] = b; tf1[c] = hf_b1[c] - mm * b;
  }
}

// ---------------------------------------------------------------------------
// K6: combined head-linear1 GEMM, bf16 MFMA, BN1 affine folded into A staging.
// BM=64 / z=8, grid (32, 2, 8) = 512 blocks (R10-proven best config).
// jobs: [0,8)=hl, [8,16)=hh, [16,32)=hf. Kc: l/h=256, f=512.
// ---------------------------------------------------------------------------
__global__ __launch_bounds__(256) void gemm_w1_mfma_kernel(
    const float* __restrict__ xl, const float* __restrict__ mp,
    const float* __restrict__ s_l, const float* __restrict__ t_l,
    const float* __restrict__ s_h, const float* __restrict__ t_h,
    const float* __restrict__ sf1, const float* __restrict__ tf1,
    const float* __restrict__ sf2, const float* __restrict__ tf2,
    const float* __restrict__ hl_w1, const float* __restrict__ hh_w1,
    const float* __restrict__ hf_w1,
    float* __restrict__ P_l, float* __restrict__ P_h, float* __restrict__ P_f) {
  __shared__ __align__(16) short As[64 * 64];
  __shared__ __align__(16) short Bs[64 * 64];
  const int jx = blockIdx.x;
  const int m0 = blockIdx.y << 6;
  const int z  = blockIdx.z;
  const float *A, *S, *T, *Wt;
  float* P;
  int N, Kdim, n0, kA0, kW0, Kc;
  if (jx < 8) {
    N = 512; Kdim = 2048; Kc = 256; Wt = hl_w1; n0 = jx << 6;
    kW0 = z * 256; kA0 = kW0; A = xl; S = s_l; T = t_l;
    P = P_l + ((size_t)z << 16);
  } else if (jx < 16) {
    N = 512; Kdim = 2048; Kc = 256; Wt = hh_w1; n0 = (jx - 8) << 6;
    kW0 = z * 256; kA0 = kW0; A = mp; S = s_h; T = t_h;
    P = P_h + ((size_t)z << 16);
  } else {
    N = 1024; Kdim = 4096; Kc = 512; Wt = hf_w1; n0 = (jx - 16) << 6;
    kW0 = z * 512;
    if (kW0 >= 2048) { A = mp; S = sf2; T = tf2; kA0 = kW0 - 2048; }
    else             { A = xl; S = sf1; T = tf1; kA0 = kW0; }
    P = P_f + ((size_t)z << 17);
  }
  const int t = threadIdx.x;
  const int rowS = t >> 2, koff = (t & 3) << 4;

  const int lane = t & 63, wav = t >> 6;
  const int r = lane & 15, kb = lane >> 4;
  int aoff[2], boff[2][4];
  #pragma unroll
  for (int kk = 0; kk < 2; ++kk) {
    int row = wav * 16 + r;
    aoff[kk] = row * 128 + ((((kk << 2) + kb) ^ (row & 7)) << 4);
    #pragma unroll
    for (int ni = 0; ni < 4; ++ni) {
      int cl = ni * 16 + r;
      boff[kk][ni] = cl * 128 + ((((kk << 2) + kb) ^ (cl & 7)) << 4);
    }
  }

  f32x4 acc[4];
  #pragma unroll
  for (int ni = 0; ni < 4; ++ni) acc[ni] = (f32x4){0.f, 0.f, 0.f, 0.f};

  for (int kt = 0; kt < Kc; kt += 64) {
    const int ka = kA0 + kt + koff;
    const float4* ap = (const float4*)&A[(size_t)(m0 + rowS) * 2048 + ka];
    const float4* sp = (const float4*)&S[ka];
    const float4* tp = (const float4*)&T[ka];
    const float4* bp = (const float4*)&Wt[(size_t)(n0 + rowS) * Kdim + kW0 + kt + koff];
    float4 fa[4], fb[4];
    #pragma unroll
    for (int j = 0; j < 4; ++j) fa[j] = ap[j];
    #pragma unroll
    for (int j = 0; j < 4; ++j) {
      float4 s4 = sp[j], t4 = tp[j];
      fa[j].x = fmaf(fa[j].x, s4.x, t4.x);
      fa[j].y = fmaf(fa[j].y, s4.y, t4.y);
      fa[j].z = fmaf(fa[j].z, s4.z, t4.z);
      fa[j].w = fmaf(fa[j].w, s4.w, t4.w);
    }
    #pragma unroll
    for (int j = 0; j < 4; ++j) fb[j] = bp[j];
    __syncthreads();
    #pragma unroll
    for (int j = 0; j < 2; ++j) {
      bf16x8 va, vb;
      va[0] = (short)f2bf(fa[2*j].x);   va[1] = (short)f2bf(fa[2*j].y);
      va[2] = (short)f2bf(fa[2*j].z);   va[3] = (short)f2bf(fa[2*j].w);
      va[4] = (short)f2bf(fa[2*j+1].x); va[5] = (short)f2bf(fa[2*j+1].y);
      va[6] = (short)f2bf(fa[2*j+1].z); va[7] = (short)f2bf(fa[2*j+1].w);
      vb[0] = (short)f2bf(fb[2*j].x);   vb[1] = (short)f2bf(fb[2*j].y);
      vb[2] = (short)f2bf(fb[2*j].z);   vb[3] = (short)f2bf(fb[2*j].w);
      vb[4] = (short)f2bf(fb[2*j+1].x); vb[5] = (short)f2bf(fb[2*j+1].y);
      vb[6] = (short)f2bf(fb[2*j+1].z); vb[7] = (short)f2bf(fb[2*j+1].w);
      int slot = (koff >> 3) + j;
      *(bf16x8*)((char*)As + rowS * 128 + ((slot ^ (rowS & 7)) << 4)) = va;
      *(bf16x8*)((char*)Bs + rowS * 128 + ((slot ^ (rowS & 7)) << 4)) = vb;
    }
    __syncthreads();
    #pragma unroll
    for (int kk = 0; kk < 2; ++kk) {
      bf16x8 a0 = *(bf16x8*)((char*)As + aoff[kk]);
      bf16x8 b0 = *(bf16x8*)((char*)Bs + boff[kk][0]);
      bf16x8 b1 = *(bf16x8*)((char*)Bs + boff[kk][1]);
      bf16x8 b2 = *(bf16x8*)((char*)Bs + boff[kk][2]);
      bf16x8 b3 = *(bf16x8*)((char*)Bs + boff[kk][3]);
      acc[0] = __builtin_amdgcn_mfma_f32_16x16x32_bf16(a0, b0, acc[0], 0, 0, 0);
      acc[1] = __builtin_amdgcn_mfma_f32_16x16x32_bf16(a0, b1, acc[1], 0, 0, 0);
      acc[2] = __builtin_amdgcn_mfma_f32_16x16x32_bf16(a0, b2, acc[2], 0, 0, 0);
      acc[3] = __builtin_amdgcn_mfma_f32_16x16x32_bf16(a0, b3, acc[3], 0, 0, 0);
    }
  }

  #pragma unroll
  for (int ni = 0; ni < 4; ++ni) {
    int cl = n0 + ni * 16 + r;
    int row = m0 + wav * 16 + kb * 4;
    #pragma unroll
    for (int g2 = 0; g2 < 4; ++g2)
      P[(size_t)(row + g2) * N + cl] = acc[ni][g2];
  }
}

// ---------------------------------------------------------------------------
// K7: heads fused epilogue (reduce 8 partial slices + bias -> BN -> ELU)
// ---------------------------------------------------------------------------
__global__ __launch_bounds__(256) void heads_fused_kernel(
    const float* __restrict__ P_l, const float* __restrict__ P_h,
    const float* __restrict__ P_f,
    const float* __restrict__ bl1, const float* __restrict__ bh1,
    const float* __restrict__ bf1,
    const float* __restrict__ g2l, const float* __restrict__ b2l,
    const float* __restrict__ g2h, const float* __restrict__ b2h,
    const float* __restrict__ g2f, const float* __restrict__ b2f,
    float* __restrict__ a2_l, float* __restrict__ a2_h, float* __restrict__ a2_f) {
  const int ci = threadIdx.x & 15;
  const int g  = threadIdx.x >> 4;
  const int cj = blockIdx.x * 16 + ci;
  const float *P, *bi, *g2, *b2;
  float* out;
  int N, cc;
  if (cj < 512)       { P = P_l; bi = bl1; g2 = g2l; b2 = b2l; out = a2_l; N = 512;  cc = cj; }
  else if (cj < 1024) { P = P_h; bi = bh1; g2 = g2h; b2 = b2h; out = a2_h; N = 512;  cc = cj - 512; }
  else                { P = P_f; bi = bf1; g2 = g2f; b2 = b2f; out = a2_f; N = 1024; cc = cj - 1024; }
  const size_t sstride = (size_t)N * 128;
  float v[8];
  float s = 0.f, q = 0.f;
  const float bias = bi[cc];
  #pragma unroll
  for (int r = 0; r < 8; ++r) {
    const size_t row = g * 8 + r;
    float acc = bias;
    #pragma unroll
    for (int z = 0; z < 8; ++z)
      acc += P[(size_t)z * sstride + row * N + cc];
    v[r] = acc; s += acc; q += acc * acc;
  }
  __shared__ float ss[16][16], qq[16][16];
  __shared__ float sm[16], sr[16];
  ss[g][ci] = s; qq[g][ci] = q;
  __syncthreads();
  if (g == 0) {
    float S = 0.f, Q = 0.f;
    #pragma unroll
    for (int j = 0; j < 16; ++j) { S += ss[j][ci]; Q += qq[j][ci]; }
    float m = S * (1.f / B_DIM);
    float var = Q * (1.f / B_DIM) - m * m;
    if (var < 0.f) var = 0.f;
    sm[ci] = m; sr[ci] = rsqrtf(var + 1e-5f);
  }
  __syncthreads();
  const float m = sm[ci], rr = sr[ci];
  const float gg = g2[cc], bb = b2[cc];
  #pragma unroll
  for (int r = 0; r < 8; ++r) {
    float xn = (v[r] - m) * rr * gg + bb;
    out[(size_t)(g * 8 + r) * N + cc] = xn > 0.f ? xn : expm1f(xn);
  }
}

// ---------------------------------------------------------------------------
// K8: combined head-linear2 split-K GEMM (fp32; R7 config). grid (12, 2, 8).
// ---------------------------------------------------------------------------
__global__ __launch_bounds__(256) void gemm_w2_kernel(
    const float* __restrict__ a2_l, const float* __restrict__ a2_h,
    const float* __restrict__ a2_f,
    const float* __restrict__ hl_w2, const float* __restrict__ hh_w2,
    const float* __restrict__ hf_w2,
    float* __restrict__ Pw) {
  const int jx = blockIdx.x;
  const int z  = blockIdx.z;
  const float *A, *Wt;
  int K, Kc, pOff, n0;
  if (jx < 4)      { A = a2_l; Wt = hl_w2; K = 512;  Kc = 64;  pOff = 0;     n0 = jx << 6; }
  else if (jx < 8) { A = a2_h; Wt = hh_w2; K = 512;  Kc = 64;  pOff = 25600; n0 = (jx - 4) << 6; }
  else             { A = a2_f; Wt = hf_w2; K = 1024; Kc = 128; pOff = 51200; n0 = (jx - 8) << 6; }
  const int kbeg = z * Kc;
  const int m0 = blockIdx.y << 6;
  __shared__ float As[32][68];
  __shared__ float Bs[32][68];
  const int t = threadIdx.x;
  const int lr = t >> 3;
  const int lk4 = (t & 7) << 2;
  const int tx = t & 15, ty = t >> 4;
  float acc[4][4] = {{0.f}};
  const float4 z4 = make_float4(0.f, 0.f, 0.f, 0.f);
  for (int k0 = kbeg; k0 < kbeg + Kc; k0 += 32) {
    float4 a0 = *(const float4*)&A[(size_t)(m0 + lr) * K + k0 + lk4];
    float4 a1 = *(const float4*)&A[(size_t)(m0 + lr + 32) * K + k0 + lk4];
    int n1 = n0 + lr, n2 = n0 + lr + 32;
    float4 b0 = (n1 < 200) ? *(const float4*)&Wt[(size_t)n1 * K + k0 + lk4] : z4;
    float4 b1 = (n2 < 200) ? *(const float4*)&Wt[(size_t)n2 * K + k0 + lk4] : z4;
    __syncthreads();
    As[lk4 + 0][lr] = a0.x; As[lk4 + 1][lr] = a0.y; As[lk4 + 2][lr] = a0.z; As[lk4 + 3][lr] = a0.w;
    As[lk4 + 0][lr + 32] = a1.x; As[lk4 + 1][lr + 32] = a1.y; As[lk4 + 2][lr + 32] = a1.z; As[lk4 + 3][lr + 32] = a1.w;
    Bs[lk4 + 0][lr] = b0.x; Bs[lk4 + 1][lr] = b0.y; Bs[lk4 + 2][lr] = b0.z; Bs[lk4 + 3][lr] = b0.w;
    Bs[lk4 + 0][lr + 32] = b1.x; Bs[lk4 + 1][lr + 32] = b1.y; Bs[lk4 + 2][lr + 32] = b1.z; Bs[lk4 + 3][lr + 32] = b1.w;
    __syncthreads();
    #pragma unroll
    for (int kk = 0; kk < 32; ++kk) {
      float4 av = *(const float4*)&As[kk][ty << 2];
      float4 bv = *(const float4*)&Bs[kk][tx << 2];
      acc[0][0] = fmaf(av.x, bv.x, acc[0][0]); acc[0][1] = fmaf(av.x, bv.y, acc[0][1]);
      acc[0][2] = fmaf(av.x, bv.z, acc[0][2]); acc[0][3] = fmaf(av.x, bv.w, acc[0][3]);
      acc[1][0] = fmaf(av.y, bv.x, acc[1][0]); acc[1][1] = fmaf(av.y, bv.y, acc[1][1]);
      acc[1][2] = fmaf(av.y, bv.z, acc[1][2]); acc[1][3] = fmaf(av.y, bv.w, acc[1][3]);
      acc[2][0] = fmaf(av.z, bv.x, acc[2][0]); acc[2][1] = fmaf(av.z, bv.y, acc[2][1]);
      acc[2][2] = fmaf(av.z, bv.z, acc[2][2]); acc[2][3] = fmaf(av.z, bv.w, acc[2][3]);
      acc[3][0] = fmaf(av.w, bv.x, acc[3][0]); acc[3][1] = fmaf(av.w, bv.y, acc[3][1]);
      acc[3][2] = fmaf(av.w, bv.z, acc[3][2]); acc[3][3] = fmaf(av.w, bv.w, acc[3][3]);
    }
  }
  float* Pz = Pw + (size_t)z * 76800 + pOff;
  #pragma unroll
  for (int i = 0; i < 4; ++i) {
    int m = m0 + (ty << 2) + i;
    #pragma unroll
    for (int j = 0; j < 4; ++j) {
      int n = n0 + (tx << 2) + j;
      if (n < 200) Pz[(size_t)m * 200 + n] = acc[i][j];
    }
  }
}

// K9: final reduce into out
__global__ void reduce_out_kernel(const float* __restrict__ P,
                                  const float* __restrict__ bl,
                                  const float* __restrict__ bh,
                                  const float* __restrict__ bf,
                                  float* __restrict__ out) {
  int i = blockIdx.x * 256 + threadIdx.x;
  if (i >= 76800) return;
  int job = i / 25600;
  int n = (i - job * 25600) % 200;
  float s = (job == 0) ? bl[n] : (job == 1) ? bh[n] : bf[n];
  for (int z = 0; z < 8; ++z) s += P[(size_t)z * 76800 + i];
  out[i] = s;
}

// ---------------------------------------------------------------------------
extern "C" void kernel_launch(void* const* d_in, const int* in_sizes, int n_in,
                              void* d_out, int out_size, void* d_ws, size_t ws_size,
                              hipStream_t stream) {
  const float* x      = (const float*)d_in[0];
  const float* g_bn_g = (const float*)d_in[1];
  const float* g_bn_b = (const float*)d_in[2];
  const float* g_w    = (const float*)d_in[3];
  const float* g_b    = (const float*)d_in[4];
  const float* e_w    = (const float*)d_in[5];
  const float* e_b    = (const float*)d_in[6];
  const float* e_g    = (const float*)d_in[7];
  const float* e_bb   = (const float*)d_in[8];
  const float* hl_g1  = (const float*)d_in[9];
  const float* hl_b1  = (const float*)d_in[10];
  const float* hl_w1  = (const float*)d_in[11];
  const float* hl_bi1 = (const float*)d_in[12];
  const float* hl_g2  = (const float*)d_in[13];
  const float* hl_b2  = (const float*)d_in[14];
  const float* hl_w2  = (const float*)d_in[15];
  const float* hl_bi2 = (const float*)d_in[16];
  const float* hh_g1  = (const float*)d_in[17];
  const float* hh_b1  = (const float*)d_in[18];
  const float* hh_w1  = (const float*)d_in[19];
  const float* hh_bi1 = (const float*)d_in[20];
  const float* hh_g2  = (const float*)d_in[21];
  const float* hh_b2  = (const float*)d_in[22];
  const float* hh_w2  = (const float*)d_in[23];
  const float* hh_bi2 = (const float*)d_in[24];
  const float* hf_g1  = (const float*)d_in[25];
  const float* hf_b1  = (const float*)d_in[26];
  const float* hf_w1  = (const float*)d_in[27];
  const float* hf_bi1 = (const float*)d_in[28];
  const float* hf_g2  = (const float*)d_in[29];
  const float* hf_b2  = (const float*)d_in[30];
  const float* hf_w2  = (const float*)d_in[31];
  const float* hf_bi2 = (const float*)d_in[32];
  float* out = (float*)d_out;

  float* W = (float*)d_ws;
  const size_t BC = (size_t)B_DIM * C_DIM;   // 262144
  float* mp   = W;
  float* ms   = mp + BC;
  float* pool = ms + BC * 4;
  float* xl   = pool + BC;
  float* a2_l = xl + BC;
  float* a2_h = a2_l + 128 * 512;
  float* a2_f = a2_h + 128 * 512;
  float* st   = a2_f + 128 * 1024;
  float* mean_mp = st;           float* rstd_mp = st + 2048;
  float* s_h  = st + 2 * 2048;   float* t_h  = st + 3 * 2048;
  float* sf2  = st + 4 * 2048;   float* tf2  = st + 5 * 2048;
  float* s_l  = st + 6 * 2048;   float* t_l  = st + 7 * 2048;
  float* sf1  = st + 8 * 2048;   float* tf1  = st + 9 * 2048;
  float* P_e  = st + 10 * 2048;                 // 8 x 262144 (reused as P_w2)
  float* P_l2 = P_e + 8 * BC;                   // 8 x 65536
  float* P_hh = P_l2 + (size_t)8 * 65536;       // 8 x 65536
  float* P_f  = P_hh + (size_t)8 * 65536;       // 8 x 131072
  float* P_w2 = P_e;

  pool_max_kernel<<<16384, 256, 0, stream>>>(x, mp, ms);

  statsmp_kernel<<<128, 256, 0, stream>>>(mp, hh_g1, hh_b1, hf_g1, hf_b1,
                                          mean_mp, rstd_mp, s_h, t_h, sf2, tf2);

  gate_select_kernel<<<128, 256, 0, stream>>>(mp, mean_mp, rstd_mp, g_bn_g, g_bn_b,
                                              g_w, g_b, ms, pool);

  gemm_e_mfma_kernel<<<dim3(32, 2, 8), 256, 0, stream>>>(pool, e_w, P_e);

  expert_fused_kernel<<<128, 256, 0, stream>>>(P_e, e_b, e_g, e_bb,
                                               hl_g1, hl_b1, hf_g1, hf_b1,
                                               xl, s_l, t_l, sf1, tf1);

  gemm_w1_mfma_kernel<<<dim3(32, 2, 8), 256, 0, stream>>>(
      xl, mp, s_l, t_l, s_h, t_h, sf1, tf1, sf2, tf2,
      hl_w1, hh_w1, hf_w1, P_l2, P_hh, P_f);

  heads_fused_kernel<<<128, 256, 0, stream>>>(
      P_l2, P_hh, P_f, hl_bi1, hh_bi1, hf_bi1,
      hl_g2, hl_b2, hh_g2, hh_b2, hf_g2, hf_b2,
      a2_l, a2_h, a2_f);

  gemm_w2_kernel<<<dim3(12, 2, 8), 256, 0, stream>>>(
      a2_l, a2_h, a2_f, hl_w2, hh_w2, hf_w2, P_w2);

  reduce_out_kernel<<<300, 256, 0, stream>>>(P_w2, hl_bi2, hh_bi2, hf_bi2, out);
}